// Round 14
// baseline (475.127 us; speedup 1.0000x reference)
//
#include <hip/hip_runtime.h>
#include <math.h>

#define NPTS 262144
#define KC 512
#define DD 64
#define MARGIN 0.02f
#define SHIFT 32.0f
#define SENTINEL -1.0f

typedef _Float16 f16x8 __attribute__((ext_vector_type(8)));
typedef float f32x4 __attribute__((ext_vector_type(4)));

// ws layout (bytes)
#define WS_GCNT  0      // int global list counter (memset each launch)
#define WS_CS16  16     // 512 f32: c_sq + SHIFT
#define WS_CSQ   2064   // 512 f32: exact c_sq (pairwise-8)
#define WS_CF16  4112   // 512*64 f16 centroids (65536 B)
#define WS_LIST  69648  // compact flagged-point list (ws-size-guarded)

__device__ __forceinline__ float csq_pairwise8(const float* row) {
    float r[8];
#pragma unroll
    for (int t = 0; t < 8; ++t) r[t] = __fmul_rn(row[t], row[t]);
#pragma unroll
    for (int b = 1; b < 8; ++b)
#pragma unroll
        for (int t = 0; t < 8; ++t)
            r[t] = __fadd_rn(r[t], __fmul_rn(row[8 * b + t], row[8 * b + t]));
    return __fadd_rn(__fadd_rn(__fadd_rn(r[0], r[1]), __fadd_rn(r[2], r[3])),
                     __fadd_rn(__fadd_rn(r[4], r[5]), __fadd_rn(r[6], r[7])));
}

__global__ __launch_bounds__(256) void prep_kernel(const float* __restrict__ c,
                                                   float* __restrict__ out_c,
                                                   _Float16* __restrict__ cf16,
                                                   float* __restrict__ cs16,
                                                   float* __restrict__ csq) {
    int j = blockIdx.x * 256 + threadIdx.x;
    if (j < KC * DD) {
        float v = c[j];
        out_c[j] = v;
        cf16[j] = (_Float16)v;  // RNE
    }
    if (j < KC) {
        float s = csq_pairwise8(c + j * DD);
        csq[j] = s;
        cs16[j] = s + SHIFT;
    }
}

// R13's clean approx kernel, byte-identical (absent from top-5 = no spill).
__global__ __launch_bounds__(256, 2) void approx_kernel(const float* __restrict__ x,
                                                        const _Float16* __restrict__ cf16,
                                                        const float* __restrict__ cs16g,
                                                        float* __restrict__ out_assign,
                                                        int* __restrict__ gcnt,
                                                        int* __restrict__ glist,
                                                        int list_cap) {
    extern __shared__ char smem[];          // [0,64K): swizzled c_f16
    float* scs = (float*)(smem + 65536);    // 512 f32: c_sq + SHIFT
    __shared__ int llist[128];
    __shared__ int lcnt, lbase;

    int tid = threadIdx.x;
    if (tid == 0) lcnt = 0;
    const uint4* src = (const uint4*)cf16;
#pragma unroll
    for (int i = 0; i < 16; ++i) {
        int chunk = tid + i * 256;          // 4096 chunks of 16B
        int row = chunk >> 3, slot = chunk & 7;
        uint4 v = src[chunk];
        *(uint4*)(smem + row * 128 + ((slot ^ (row & 7)) << 4)) = v;
    }
    scs[tid] = cs16g[tid];
    scs[tid + 256] = cs16g[tid + 256];
    __syncthreads();

    int wid = tid >> 6, lane = tid & 63;
    int pbase = blockIdx.x * 128 + wid * 32;
    int lrow = lane & 15, lgrp = lane >> 4;

    f16x8 a[2][2];
#pragma unroll
    for (int s = 0; s < 2; ++s)
#pragma unroll
        for (int kk = 0; kk < 2; ++kk) {
            const float4* p = (const float4*)(x + (size_t)(pbase + s * 16 + lrow) * DD
                                              + kk * 32 + lgrp * 8);
            float4 u0 = p[0], u1 = p[1];
            f16x8 t;
            t[0] = (_Float16)u0.x; t[1] = (_Float16)u0.y;
            t[2] = (_Float16)u0.z; t[3] = (_Float16)u0.w;
            t[4] = (_Float16)u1.x; t[5] = (_Float16)u1.y;
            t[6] = (_Float16)u1.z; t[7] = (_Float16)u1.w;
            a[s][kk] = t;
        }

    unsigned b1[2][4], b2[2][4];
#pragma unroll
    for (int s = 0; s < 2; ++s)
#pragma unroll
        for (int r = 0; r < 4; ++r) { b1[s][r] = 0xFFFFFFFFu; b2[s][r] = 0xFFFFFFFFu; }

    int base0 = lrow * 128 + ((lgrp ^ (lane & 7)) << 4);
    int base1 = base0 ^ 64;
    int centv = lrow;

    for (int ct = 0; ct < 32; ++ct) {
        f16x8 bk0 = *(const f16x8*)(smem + base0);
        f16x8 bk1 = *(const f16x8*)(smem + base1);
        float cs = scs[centv];
        f32x4 acc0 = {0.f, 0.f, 0.f, 0.f}, acc1 = {0.f, 0.f, 0.f, 0.f};
        acc0 = __builtin_amdgcn_mfma_f32_16x16x32_f16(a[0][0], bk0, acc0, 0, 0, 0);
        acc0 = __builtin_amdgcn_mfma_f32_16x16x32_f16(a[0][1], bk1, acc0, 0, 0, 0);
        acc1 = __builtin_amdgcn_mfma_f32_16x16x32_f16(a[1][0], bk0, acc1, 0, 0, 0);
        acc1 = __builtin_amdgcn_mfma_f32_16x16x32_f16(a[1][1], bk1, acc1, 0, 0, 0);
#pragma unroll
        for (int r = 0; r < 4; ++r) {
            float d0 = __builtin_fmaf(-2.0f, acc0[r], cs);
            float d1 = __builtin_fmaf(-2.0f, acc1[r], cs);
            unsigned k0 = (__float_as_uint(d0) & 0xFFFFFE00u) | (unsigned)centv;
            unsigned k1 = (__float_as_uint(d1) & 0xFFFFFE00u) | (unsigned)centv;
            unsigned m0 = max(b1[0][r], k0);
            b1[0][r] = min(b1[0][r], k0);
            b2[0][r] = min(b2[0][r], m0);
            unsigned m1 = max(b1[1][r], k1);
            b1[1][r] = min(b1[1][r], k1);
            b2[1][r] = min(b2[1][r], m1);
        }
        base0 += 2048; base1 += 2048; centv += 16;
    }

#pragma unroll
    for (int d = 1; d < 16; d <<= 1) {
#pragma unroll
        for (int s = 0; s < 2; ++s)
#pragma unroll
            for (int r = 0; r < 4; ++r) {
                unsigned o1 = (unsigned)__shfl_xor((int)b1[s][r], d);
                unsigned o2 = (unsigned)__shfl_xor((int)b2[s][r], d);
                unsigned mx = max(b1[s][r], o1);
                b1[s][r] = min(b1[s][r], o1);
                b2[s][r] = min(min(b2[s][r], o2), mx);
            }
    }

    if (lrow == 0) {
#pragma unroll
        for (int s = 0; s < 2; ++s)
#pragma unroll
            for (int r = 0; r < 4; ++r) {
                int p = pbase + s * 16 + lgrp * 4 + r;
                unsigned w = b1[s][r];
                float d1 = __uint_as_float(w & 0xFFFFFE00u);
                float d2 = __uint_as_float(b2[s][r] & 0xFFFFFE00u);
                out_assign[p] = (float)(w & 0x1FFu);
                if (d2 - d1 <= MARGIN) {
                    int t = atomicAdd(&lcnt, 1);
                    llist[t] = p;
                }
            }
    }
    __syncthreads();
    int n = lcnt;
    if (tid == 0) lbase = n ? atomicAdd(gcnt, n) : 0;
    __syncthreads();
    for (int t = tid; t < n; t += 256) {
        int idx = lbase + t;
        if (idx < list_cap) glist[idx] = llist[t];
        else out_assign[llist[t]] = SENTINEL;   // ws too small: fallback fixes
    }
}

// Rescore v2: 8 LANES PER POINT (k-split by 8) -- serial depth 512->64 and
// threads 12K->98K, so load latency is both shorter and TLP-hidden (R13:
// thread-per-point at F~12K = 190 waves device-wide, fully exposed latency,
// 221us). Each lane computes the FULL 64-dim dot with the exact R1 op
// sequence (bit-identical wherever it runs); 8-lane packed-key min reduce.
__global__ __launch_bounds__(256) void rescore_kernel(const float* __restrict__ x,
                                                      const float* __restrict__ c,
                                                      const float* __restrict__ csq,
                                                      const int* __restrict__ gcnt,
                                                      const int* __restrict__ glist,
                                                      int list_cap,
                                                      float* __restrict__ out_assign) {
    __shared__ float xs[32][68];   // stride 68: groups hit banks 4*grp+d, no conflict
    __shared__ float scsq[KC];
    __shared__ int pidx[32];

    int n = *gcnt;
    if (n > list_cap) n = list_cap;
    int tid = threadIdx.x;
    scsq[tid] = csq[tid];
    scsq[tid + 256] = csq[tid + 256];
    int grp = tid >> 3, gg = tid & 7;

    for (int base = blockIdx.x * 32; base < n; base += gridDim.x * 32) {
        int cnt = n - base;
        if (cnt > 32) cnt = 32;
        __syncthreads();                        // xs/pidx reuse barrier
        if (tid < cnt) pidx[tid] = glist[base + tid];
        __syncthreads();
        // Stage cnt x-rows: 8 threads per row, 32B each (coalesced per row).
        if ((tid >> 3) < cnt) {
            int pi = pidx[tid >> 3];
            const float4* xp = (const float4*)(x + (size_t)pi * DD) + (tid & 7) * 2;
            float4 v0 = xp[0], v1 = xp[1];
            float* dst = &xs[tid >> 3][(tid & 7) * 8];
            dst[0] = v0.x; dst[1] = v0.y; dst[2] = v0.z; dst[3] = v0.w;
            dst[4] = v1.x; dst[5] = v1.y; dst[6] = v1.z; dst[7] = v1.w;
        }
        __syncthreads();
        if (grp >= cnt) continue;

        const float* xr = xs[grp];
        // x_sq: numpy pairwise-8, identical ops (LDS-read values bit-equal).
        float r8[8];
#pragma unroll
        for (int e = 0; e < 8; ++e) r8[e] = __fmul_rn(xr[e], xr[e]);
#pragma unroll
        for (int blk = 1; blk < 8; ++blk)
#pragma unroll
            for (int e = 0; e < 8; ++e)
                r8[e] = __fadd_rn(r8[e], __fmul_rn(xr[8 * blk + e], xr[8 * blk + e]));
        float x_sq = __fadd_rn(__fadd_rn(__fadd_rn(r8[0], r8[1]), __fadd_rn(r8[2], r8[3])),
                               __fadd_rn(__fadd_rn(r8[4], r8[5]), __fadd_rn(r8[6], r8[7])));

        unsigned long long best = ~0ull;
#pragma unroll 1
        for (int j = 0; j < 64; ++j) {
            int k = j * 8 + gg;
            const float4* cv = (const float4*)(c + (size_t)k * DD);
            float a0 = 0.f, a1 = 0.f, a2 = 0.f, a3 = 0.f;
#pragma unroll
            for (int q = 0; q < 16; ++q) {
                float4 cq = cv[q];
                a0 = __fmaf_rn(xr[4 * q + 0], cq.x, a0);
                a1 = __fmaf_rn(xr[4 * q + 1], cq.y, a1);
                a2 = __fmaf_rn(xr[4 * q + 2], cq.z, a2);
                a3 = __fmaf_rn(xr[4 * q + 3], cq.w, a3);
            }
            float acc = __fadd_rn(__fadd_rn(a0, a1), __fadd_rn(a2, a3));
            float tt = __fadd_rn(x_sq, scsq[k]);
            float dist = __fmaf_rn(-2.0f, acc, tt);
            unsigned long long key =
                ((unsigned long long)__float_as_uint(dist) << 32) | (unsigned)k;
            best = best < key ? best : key;
        }
        // Reduce across the 8 lanes of the group (xor 1,2,4 stays in-group).
#pragma unroll
        for (int m = 1; m < 8; m <<= 1) {
            unsigned hi = (unsigned)__shfl_xor((int)(best >> 32), m);
            unsigned lo = (unsigned)__shfl_xor((int)(best & 0xFFFFFFFFull), m);
            unsigned long long o = ((unsigned long long)hi << 32) | lo;
            best = best < o ? best : o;
        }
        if (gg == 0) out_assign[pidx[grp]] = (float)(unsigned)(best & 0xFFFFFFFFull);
    }
}

// Fallback: repairs any SENTINEL left by list overflow (normally zero work).
__global__ __launch_bounds__(256) void fallback_kernel(const float* __restrict__ x,
                                                       const float* __restrict__ c,
                                                       const float* __restrict__ csq,
                                                       float* __restrict__ out_assign) {
    int p = blockIdx.x * 256 + threadIdx.x;
    int lane = threadIdx.x & 63;
    float v = out_assign[p];
    unsigned long long mask = __ballot(v < 0.0f);
    int wbase = p & ~63;

    while (mask) {
        int b = __ffsll((long long)mask) - 1;
        mask &= mask - 1;
        int i = wbase + b;
        const float* xr = x + (size_t)i * DD;

        float r8[8];
#pragma unroll
        for (int e = 0; e < 8; ++e) r8[e] = __fmul_rn(xr[e], xr[e]);
#pragma unroll
        for (int blk = 1; blk < 8; ++blk)
#pragma unroll
            for (int e = 0; e < 8; ++e)
                r8[e] = __fadd_rn(r8[e], __fmul_rn(xr[8 * blk + e], xr[8 * blk + e]));
        float x_sq = __fadd_rn(__fadd_rn(__fadd_rn(r8[0], r8[1]), __fadd_rn(r8[2], r8[3])),
                               __fadd_rn(__fadd_rn(r8[4], r8[5]), __fadd_rn(r8[6], r8[7])));

        unsigned long long best = ~0ull;
#pragma unroll 1
        for (int j = 0; j < 8; ++j) {
            int k = j * 64 + lane;
            const float* crow = c + (size_t)k * DD;
            float a0 = 0.f, a1 = 0.f, a2 = 0.f, a3 = 0.f;
#pragma unroll
            for (int d = 0; d < DD; d += 4) {
                a0 = __fmaf_rn(xr[d + 0], crow[d + 0], a0);
                a1 = __fmaf_rn(xr[d + 1], crow[d + 1], a1);
                a2 = __fmaf_rn(xr[d + 2], crow[d + 2], a2);
                a3 = __fmaf_rn(xr[d + 3], crow[d + 3], a3);
            }
            float acc = __fadd_rn(__fadd_rn(a0, a1), __fadd_rn(a2, a3));
            float tt = __fadd_rn(x_sq, csq[k]);
            float dist = __fmaf_rn(-2.0f, acc, tt);
            unsigned long long key =
                ((unsigned long long)__float_as_uint(dist) << 32) | (unsigned)k;
            best = best < key ? best : key;
        }
#pragma unroll
        for (int dd = 1; dd < 64; dd <<= 1) {
            unsigned hi = (unsigned)__shfl_xor((int)(best >> 32), dd);
            unsigned lo = (unsigned)__shfl_xor((int)(best & 0xFFFFFFFFull), dd);
            unsigned long long o = ((unsigned long long)hi << 32) | lo;
            best = best < o ? best : o;
        }
        if (lane == 0) out_assign[i] = (float)(unsigned)(best & 0xFFFFFFFFull);
    }
}

extern "C" void kernel_launch(void* const* d_in, const int* in_sizes, int n_in,
                              void* d_out, int out_size, void* d_ws, size_t ws_size,
                              hipStream_t stream) {
    const float* x = (const float*)d_in[0];
    const float* c = (const float*)d_in[1];
    float* out = (float*)d_out;
    float* out_assign = out + KC * DD;

    char* ws = (char*)d_ws;
    int* gcnt = (int*)(ws + WS_GCNT);
    float* cs16 = (float*)(ws + WS_CS16);
    float* csq = (float*)(ws + WS_CSQ);
    _Float16* cf16 = (_Float16*)(ws + WS_CF16);
    int* glist = (int*)(ws + WS_LIST);
    int list_cap = 0;
    if (ws_size > WS_LIST + 4) {
        size_t cap = (ws_size - WS_LIST) / 4;
        list_cap = cap > NPTS ? NPTS : (int)cap;
    }

    hipMemsetAsync(gcnt, 0, 16, stream);
    prep_kernel<<<(KC * DD + 255) / 256, 256, 0, stream>>>(c, out, cf16, cs16, csq);
    approx_kernel<<<NPTS / 128, 256, 67584, stream>>>(x, cf16, cs16, out_assign,
                                                      gcnt, glist, list_cap);
    rescore_kernel<<<512, 256, 0, stream>>>(x, c, csq, gcnt, glist, list_cap,
                                            out_assign);
    fallback_kernel<<<NPTS / 256, 256, 0, stream>>>(x, c, csq, out_assign);
}

// Round 15
// 436.759 us; speedup vs baseline: 1.0878x; 1.0878x over previous
//
#include <hip/hip_runtime.h>
#include <math.h>

#define NPTS 262144
#define KC 512
#define DD 64
#define MARGIN 0.02f
#define SHIFT 32.0f
#define SENTINEL -1.0f

typedef _Float16 f16x8 __attribute__((ext_vector_type(8)));
typedef float f32x4 __attribute__((ext_vector_type(4)));

// ws layout (bytes)
#define WS_GCNT  0      // int global list counter (memset each launch)
#define WS_CS16  16     // 512 f32: c_sq + SHIFT
#define WS_CSQ   2064   // 512 f32: exact c_sq (pairwise-8)
#define WS_CF16  4112   // 512*64 f16 centroids (65536 B)
#define WS_LIST  69648  // compact flagged-point list (ws-size-guarded)

__device__ __forceinline__ float csq_pairwise8(const float* row) {
    float r[8];
#pragma unroll
    for (int t = 0; t < 8; ++t) r[t] = __fmul_rn(row[t], row[t]);
#pragma unroll
    for (int b = 1; b < 8; ++b)
#pragma unroll
        for (int t = 0; t < 8; ++t)
            r[t] = __fadd_rn(r[t], __fmul_rn(row[8 * b + t], row[8 * b + t]));
    return __fadd_rn(__fadd_rn(__fadd_rn(r[0], r[1]), __fadd_rn(r[2], r[3])),
                     __fadd_rn(__fadd_rn(r[4], r[5]), __fadd_rn(r[6], r[7])));
}

__global__ __launch_bounds__(256) void prep_kernel(const float* __restrict__ c,
                                                   float* __restrict__ out_c,
                                                   _Float16* __restrict__ cf16,
                                                   float* __restrict__ cs16,
                                                   float* __restrict__ csq) {
    int j = blockIdx.x * 256 + threadIdx.x;
    if (j < KC * DD) {
        float v = c[j];
        out_c[j] = v;
        cf16[j] = (_Float16)v;  // RNE
    }
    if (j < KC) {
        float s = csq_pairwise8(c + j * DD);
        csq[j] = s;
        cs16[j] = s + SHIFT;
    }
}

// R13's clean approx kernel, byte-identical (no spill, no atomics storm).
__global__ __launch_bounds__(256, 2) void approx_kernel(const float* __restrict__ x,
                                                        const _Float16* __restrict__ cf16,
                                                        const float* __restrict__ cs16g,
                                                        float* __restrict__ out_assign,
                                                        int* __restrict__ gcnt,
                                                        int* __restrict__ glist,
                                                        int list_cap) {
    extern __shared__ char smem[];          // [0,64K): swizzled c_f16
    float* scs = (float*)(smem + 65536);    // 512 f32: c_sq + SHIFT
    __shared__ int llist[128];
    __shared__ int lcnt, lbase;

    int tid = threadIdx.x;
    if (tid == 0) lcnt = 0;
    const uint4* src = (const uint4*)cf16;
#pragma unroll
    for (int i = 0; i < 16; ++i) {
        int chunk = tid + i * 256;          // 4096 chunks of 16B
        int row = chunk >> 3, slot = chunk & 7;
        uint4 v = src[chunk];
        *(uint4*)(smem + row * 128 + ((slot ^ (row & 7)) << 4)) = v;
    }
    scs[tid] = cs16g[tid];
    scs[tid + 256] = cs16g[tid + 256];
    __syncthreads();

    int wid = tid >> 6, lane = tid & 63;
    int pbase = blockIdx.x * 128 + wid * 32;
    int lrow = lane & 15, lgrp = lane >> 4;

    f16x8 a[2][2];
#pragma unroll
    for (int s = 0; s < 2; ++s)
#pragma unroll
        for (int kk = 0; kk < 2; ++kk) {
            const float4* p = (const float4*)(x + (size_t)(pbase + s * 16 + lrow) * DD
                                              + kk * 32 + lgrp * 8);
            float4 u0 = p[0], u1 = p[1];
            f16x8 t;
            t[0] = (_Float16)u0.x; t[1] = (_Float16)u0.y;
            t[2] = (_Float16)u0.z; t[3] = (_Float16)u0.w;
            t[4] = (_Float16)u1.x; t[5] = (_Float16)u1.y;
            t[6] = (_Float16)u1.z; t[7] = (_Float16)u1.w;
            a[s][kk] = t;
        }

    unsigned b1[2][4], b2[2][4];
#pragma unroll
    for (int s = 0; s < 2; ++s)
#pragma unroll
        for (int r = 0; r < 4; ++r) { b1[s][r] = 0xFFFFFFFFu; b2[s][r] = 0xFFFFFFFFu; }

    int base0 = lrow * 128 + ((lgrp ^ (lane & 7)) << 4);
    int base1 = base0 ^ 64;
    int centv = lrow;

    for (int ct = 0; ct < 32; ++ct) {
        f16x8 bk0 = *(const f16x8*)(smem + base0);
        f16x8 bk1 = *(const f16x8*)(smem + base1);
        float cs = scs[centv];
        f32x4 acc0 = {0.f, 0.f, 0.f, 0.f}, acc1 = {0.f, 0.f, 0.f, 0.f};
        acc0 = __builtin_amdgcn_mfma_f32_16x16x32_f16(a[0][0], bk0, acc0, 0, 0, 0);
        acc0 = __builtin_amdgcn_mfma_f32_16x16x32_f16(a[0][1], bk1, acc0, 0, 0, 0);
        acc1 = __builtin_amdgcn_mfma_f32_16x16x32_f16(a[1][0], bk0, acc1, 0, 0, 0);
        acc1 = __builtin_amdgcn_mfma_f32_16x16x32_f16(a[1][1], bk1, acc1, 0, 0, 0);
#pragma unroll
        for (int r = 0; r < 4; ++r) {
            float d0 = __builtin_fmaf(-2.0f, acc0[r], cs);
            float d1 = __builtin_fmaf(-2.0f, acc1[r], cs);
            unsigned k0 = (__float_as_uint(d0) & 0xFFFFFE00u) | (unsigned)centv;
            unsigned k1 = (__float_as_uint(d1) & 0xFFFFFE00u) | (unsigned)centv;
            unsigned m0 = max(b1[0][r], k0);
            b1[0][r] = min(b1[0][r], k0);
            b2[0][r] = min(b2[0][r], m0);
            unsigned m1 = max(b1[1][r], k1);
            b1[1][r] = min(b1[1][r], k1);
            b2[1][r] = min(b2[1][r], m1);
        }
        base0 += 2048; base1 += 2048; centv += 16;
    }

#pragma unroll
    for (int d = 1; d < 16; d <<= 1) {
#pragma unroll
        for (int s = 0; s < 2; ++s)
#pragma unroll
            for (int r = 0; r < 4; ++r) {
                unsigned o1 = (unsigned)__shfl_xor((int)b1[s][r], d);
                unsigned o2 = (unsigned)__shfl_xor((int)b2[s][r], d);
                unsigned mx = max(b1[s][r], o1);
                b1[s][r] = min(b1[s][r], o1);
                b2[s][r] = min(min(b2[s][r], o2), mx);
            }
    }

    if (lrow == 0) {
#pragma unroll
        for (int s = 0; s < 2; ++s)
#pragma unroll
            for (int r = 0; r < 4; ++r) {
                int p = pbase + s * 16 + lgrp * 4 + r;
                unsigned w = b1[s][r];
                float d1 = __uint_as_float(w & 0xFFFFFE00u);
                float d2 = __uint_as_float(b2[s][r] & 0xFFFFFE00u);
                out_assign[p] = (float)(w & 0x1FFu);
                if (d2 - d1 <= MARGIN) {
                    int t = atomicAdd(&lcnt, 1);
                    llist[t] = p;
                }
            }
    }
    __syncthreads();
    int n = lcnt;
    if (tid == 0) lbase = n ? atomicAdd(gcnt, n) : 0;
    __syncthreads();
    for (int t = tid; t < n; t += 256) {
        int idx = lbase + t;
        if (idx < list_cap) glist[idx] = llist[t];
        else out_assign[llist[t]] = SENTINEL;   // ws too small: fallback fixes
    }
}

// Rescore v3: R13's structure (thread-per-point over the compact list;
// k-loop WAVE-UNIFORM -> centroid rows arrive as broadcast s_loads -- the
// proven-good access pattern) + unroll(4) for ILP: 4 independent
// s_load+FMA chains in flight cover the ~200cy scalar-load latency that
// R13 left fully exposed (221us at 3% occupancy). R14's lane-split k
// (uncoalesced per-lane rows) was the wrong fix: 352us.
__global__ __launch_bounds__(256) void rescore_kernel(const float* __restrict__ x,
                                                      const float* __restrict__ c,
                                                      const float* __restrict__ csq,
                                                      const int* __restrict__ gcnt,
                                                      const int* __restrict__ glist,
                                                      int list_cap,
                                                      float* __restrict__ out_assign) {
    int n = *gcnt;
    if (n > list_cap) n = list_cap;
    for (int idx = blockIdx.x * 256 + threadIdx.x; idx < n; idx += 256 * 256) {
        int i = glist[idx];
        float xv[DD];
        const float4* xp = (const float4*)(x + (size_t)i * DD);
#pragma unroll
        for (int q = 0; q < DD / 4; ++q) {
            float4 v = xp[q];
            xv[4 * q + 0] = v.x; xv[4 * q + 1] = v.y;
            xv[4 * q + 2] = v.z; xv[4 * q + 3] = v.w;
        }
        float r[8];
#pragma unroll
        for (int t = 0; t < 8; ++t) r[t] = __fmul_rn(xv[t], xv[t]);
#pragma unroll
        for (int b = 1; b < 8; ++b)
#pragma unroll
            for (int t = 0; t < 8; ++t)
                r[t] = __fadd_rn(r[t], __fmul_rn(xv[8 * b + t], xv[8 * b + t]));
        float x_sq = __fadd_rn(__fadd_rn(__fadd_rn(r[0], r[1]), __fadd_rn(r[2], r[3])),
                               __fadd_rn(__fadd_rn(r[4], r[5]), __fadd_rn(r[6], r[7])));
        float best = INFINITY;
        int best_k = 0;
        // unroll 4: independent load/FMA chains per k; the best/best_k update
        // chain keeps program order -> first-index-wins semantics unchanged.
#pragma unroll 4
        for (int k = 0; k < KC; ++k) {
            const float* crow = c + (size_t)k * DD;  // wave-uniform -> s_load
            float a0 = 0.f, a1 = 0.f, a2 = 0.f, a3 = 0.f;
#pragma unroll
            for (int d = 0; d < DD; d += 4) {
                a0 = __fmaf_rn(xv[d + 0], crow[d + 0], a0);
                a1 = __fmaf_rn(xv[d + 1], crow[d + 1], a1);
                a2 = __fmaf_rn(xv[d + 2], crow[d + 2], a2);
                a3 = __fmaf_rn(xv[d + 3], crow[d + 3], a3);
            }
            float acc = __fadd_rn(__fadd_rn(a0, a1), __fadd_rn(a2, a3));
            float t = __fadd_rn(x_sq, csq[k]);
            float dist = __fmaf_rn(-2.0f, acc, t);
            if (dist < best) { best = dist; best_k = k; }  // strict <: first wins
        }
        out_assign[i] = (float)best_k;
    }
}

// Fallback: repairs any SENTINEL left by list overflow (normally zero work).
__global__ __launch_bounds__(256) void fallback_kernel(const float* __restrict__ x,
                                                       const float* __restrict__ c,
                                                       const float* __restrict__ csq,
                                                       float* __restrict__ out_assign) {
    int p = blockIdx.x * 256 + threadIdx.x;
    int lane = threadIdx.x & 63;
    float v = out_assign[p];
    unsigned long long mask = __ballot(v < 0.0f);
    int wbase = p & ~63;

    while (mask) {
        int b = __ffsll((long long)mask) - 1;
        mask &= mask - 1;
        int i = wbase + b;
        const float* xr = x + (size_t)i * DD;

        float r8[8];
#pragma unroll
        for (int e = 0; e < 8; ++e) r8[e] = __fmul_rn(xr[e], xr[e]);
#pragma unroll
        for (int blk = 1; blk < 8; ++blk)
#pragma unroll
            for (int e = 0; e < 8; ++e)
                r8[e] = __fadd_rn(r8[e], __fmul_rn(xr[8 * blk + e], xr[8 * blk + e]));
        float x_sq = __fadd_rn(__fadd_rn(__fadd_rn(r8[0], r8[1]), __fadd_rn(r8[2], r8[3])),
                               __fadd_rn(__fadd_rn(r8[4], r8[5]), __fadd_rn(r8[6], r8[7])));

        unsigned long long best = ~0ull;
#pragma unroll 1
        for (int j = 0; j < 8; ++j) {
            int k = j * 64 + lane;
            const float* crow = c + (size_t)k * DD;
            float a0 = 0.f, a1 = 0.f, a2 = 0.f, a3 = 0.f;
#pragma unroll
            for (int d = 0; d < DD; d += 4) {
                a0 = __fmaf_rn(xr[d + 0], crow[d + 0], a0);
                a1 = __fmaf_rn(xr[d + 1], crow[d + 1], a1);
                a2 = __fmaf_rn(xr[d + 2], crow[d + 2], a2);
                a3 = __fmaf_rn(xr[d + 3], crow[d + 3], a3);
            }
            float acc = __fadd_rn(__fadd_rn(a0, a1), __fadd_rn(a2, a3));
            float tt = __fadd_rn(x_sq, csq[k]);
            float dist = __fmaf_rn(-2.0f, acc, tt);
            unsigned long long key =
                ((unsigned long long)__float_as_uint(dist) << 32) | (unsigned)k;
            best = best < key ? best : key;
        }
#pragma unroll
        for (int dd = 1; dd < 64; dd <<= 1) {
            unsigned hi = (unsigned)__shfl_xor((int)(best >> 32), dd);
            unsigned lo = (unsigned)__shfl_xor((int)(best & 0xFFFFFFFFull), dd);
            unsigned long long o = ((unsigned long long)hi << 32) | lo;
            best = best < o ? best : o;
        }
        if (lane == 0) out_assign[i] = (float)(unsigned)(best & 0xFFFFFFFFull);
    }
}

extern "C" void kernel_launch(void* const* d_in, const int* in_sizes, int n_in,
                              void* d_out, int out_size, void* d_ws, size_t ws_size,
                              hipStream_t stream) {
    const float* x = (const float*)d_in[0];
    const float* c = (const float*)d_in[1];
    float* out = (float*)d_out;
    float* out_assign = out + KC * DD;

    char* ws = (char*)d_ws;
    int* gcnt = (int*)(ws + WS_GCNT);
    float* cs16 = (float*)(ws + WS_CS16);
    float* csq = (float*)(ws + WS_CSQ);
    _Float16* cf16 = (_Float16*)(ws + WS_CF16);
    int* glist = (int*)(ws + WS_LIST);
    int list_cap = 0;
    if (ws_size > WS_LIST + 4) {
        size_t cap = (ws_size - WS_LIST) / 4;
        list_cap = cap > NPTS ? NPTS : (int)cap;
    }

    hipMemsetAsync(gcnt, 0, 16, stream);
    prep_kernel<<<(KC * DD + 255) / 256, 256, 0, stream>>>(c, out, cf16, cs16, csq);
    approx_kernel<<<NPTS / 128, 256, 67584, stream>>>(x, cf16, cs16, out_assign,
                                                      gcnt, glist, list_cap);
    rescore_kernel<<<256, 256, 0, stream>>>(x, c, csq, gcnt, glist, list_cap,
                                            out_assign);
    fallback_kernel<<<NPTS / 256, 256, 0, stream>>>(x, c, csq, out_assign);
}

// Round 16
// 195.022 us; speedup vs baseline: 2.4363x; 2.2395x over previous
//
#include <hip/hip_runtime.h>
#include <math.h>

#define NPTS 262144
#define KC 512
#define DD 64
#define MARGIN 0.02f
#define SHIFT 32.0f
#define SENTINEL -1.0f
#define CSTRIDE 68            // f32 row stride in LDS: 272B, 16B-aligned, banks spread

typedef _Float16 f16x8 __attribute__((ext_vector_type(8)));
typedef float f32x4 __attribute__((ext_vector_type(4)));

// ws layout (bytes)
#define WS_GCNT  0      // int global list counter (memset each launch)
#define WS_CS16  16     // 512 f32: c_sq + SHIFT
#define WS_CSQ   2064   // 512 f32: exact c_sq (pairwise-8)
#define WS_CF16  4112   // 512*64 f16 centroids (65536 B)
#define WS_LIST  69648  // compact flagged-point list (ws-size-guarded)

__device__ __forceinline__ float csq_pairwise8(const float* row) {
    float r[8];
#pragma unroll
    for (int t = 0; t < 8; ++t) r[t] = __fmul_rn(row[t], row[t]);
#pragma unroll
    for (int b = 1; b < 8; ++b)
#pragma unroll
        for (int t = 0; t < 8; ++t)
            r[t] = __fadd_rn(r[t], __fmul_rn(row[8 * b + t], row[8 * b + t]));
    return __fadd_rn(__fadd_rn(__fadd_rn(r[0], r[1]), __fadd_rn(r[2], r[3])),
                     __fadd_rn(__fadd_rn(r[4], r[5]), __fadd_rn(r[6], r[7])));
}

__global__ __launch_bounds__(256) void prep_kernel(const float* __restrict__ c,
                                                   float* __restrict__ out_c,
                                                   _Float16* __restrict__ cf16,
                                                   float* __restrict__ cs16,
                                                   float* __restrict__ csq) {
    int j = blockIdx.x * 256 + threadIdx.x;
    if (j < KC * DD) {
        float v = c[j];
        out_c[j] = v;
        cf16[j] = (_Float16)v;  // RNE
    }
    if (j < KC) {
        float s = csq_pairwise8(c + j * DD);
        csq[j] = s;
        cs16[j] = s + SHIFT;
    }
}

// R13/R15's clean approx kernel, byte-identical (no spill, LDS-list compaction).
__global__ __launch_bounds__(256, 2) void approx_kernel(const float* __restrict__ x,
                                                        const _Float16* __restrict__ cf16,
                                                        const float* __restrict__ cs16g,
                                                        float* __restrict__ out_assign,
                                                        int* __restrict__ gcnt,
                                                        int* __restrict__ glist,
                                                        int list_cap) {
    extern __shared__ char smem[];          // [0,64K): swizzled c_f16
    float* scs = (float*)(smem + 65536);    // 512 f32: c_sq + SHIFT
    __shared__ int llist[128];
    __shared__ int lcnt, lbase;

    int tid = threadIdx.x;
    if (tid == 0) lcnt = 0;
    const uint4* src = (const uint4*)cf16;
#pragma unroll
    for (int i = 0; i < 16; ++i) {
        int chunk = tid + i * 256;          // 4096 chunks of 16B
        int row = chunk >> 3, slot = chunk & 7;
        uint4 v = src[chunk];
        *(uint4*)(smem + row * 128 + ((slot ^ (row & 7)) << 4)) = v;
    }
    scs[tid] = cs16g[tid];
    scs[tid + 256] = cs16g[tid + 256];
    __syncthreads();

    int wid = tid >> 6, lane = tid & 63;
    int pbase = blockIdx.x * 128 + wid * 32;
    int lrow = lane & 15, lgrp = lane >> 4;

    f16x8 a[2][2];
#pragma unroll
    for (int s = 0; s < 2; ++s)
#pragma unroll
        for (int kk = 0; kk < 2; ++kk) {
            const float4* p = (const float4*)(x + (size_t)(pbase + s * 16 + lrow) * DD
                                              + kk * 32 + lgrp * 8);
            float4 u0 = p[0], u1 = p[1];
            f16x8 t;
            t[0] = (_Float16)u0.x; t[1] = (_Float16)u0.y;
            t[2] = (_Float16)u0.z; t[3] = (_Float16)u0.w;
            t[4] = (_Float16)u1.x; t[5] = (_Float16)u1.y;
            t[6] = (_Float16)u1.z; t[7] = (_Float16)u1.w;
            a[s][kk] = t;
        }

    unsigned b1[2][4], b2[2][4];
#pragma unroll
    for (int s = 0; s < 2; ++s)
#pragma unroll
        for (int r = 0; r < 4; ++r) { b1[s][r] = 0xFFFFFFFFu; b2[s][r] = 0xFFFFFFFFu; }

    int base0 = lrow * 128 + ((lgrp ^ (lane & 7)) << 4);
    int base1 = base0 ^ 64;
    int centv = lrow;

    for (int ct = 0; ct < 32; ++ct) {
        f16x8 bk0 = *(const f16x8*)(smem + base0);
        f16x8 bk1 = *(const f16x8*)(smem + base1);
        float cs = scs[centv];
        f32x4 acc0 = {0.f, 0.f, 0.f, 0.f}, acc1 = {0.f, 0.f, 0.f, 0.f};
        acc0 = __builtin_amdgcn_mfma_f32_16x16x32_f16(a[0][0], bk0, acc0, 0, 0, 0);
        acc0 = __builtin_amdgcn_mfma_f32_16x16x32_f16(a[0][1], bk1, acc0, 0, 0, 0);
        acc1 = __builtin_amdgcn_mfma_f32_16x16x32_f16(a[1][0], bk0, acc1, 0, 0, 0);
        acc1 = __builtin_amdgcn_mfma_f32_16x16x32_f16(a[1][1], bk1, acc1, 0, 0, 0);
#pragma unroll
        for (int r = 0; r < 4; ++r) {
            float d0 = __builtin_fmaf(-2.0f, acc0[r], cs);
            float d1 = __builtin_fmaf(-2.0f, acc1[r], cs);
            unsigned k0 = (__float_as_uint(d0) & 0xFFFFFE00u) | (unsigned)centv;
            unsigned k1 = (__float_as_uint(d1) & 0xFFFFFE00u) | (unsigned)centv;
            unsigned m0 = max(b1[0][r], k0);
            b1[0][r] = min(b1[0][r], k0);
            b2[0][r] = min(b2[0][r], m0);
            unsigned m1 = max(b1[1][r], k1);
            b1[1][r] = min(b1[1][r], k1);
            b2[1][r] = min(b2[1][r], m1);
        }
        base0 += 2048; base1 += 2048; centv += 16;
    }

#pragma unroll
    for (int d = 1; d < 16; d <<= 1) {
#pragma unroll
        for (int s = 0; s < 2; ++s)
#pragma unroll
            for (int r = 0; r < 4; ++r) {
                unsigned o1 = (unsigned)__shfl_xor((int)b1[s][r], d);
                unsigned o2 = (unsigned)__shfl_xor((int)b2[s][r], d);
                unsigned mx = max(b1[s][r], o1);
                b1[s][r] = min(b1[s][r], o1);
                b2[s][r] = min(min(b2[s][r], o2), mx);
            }
    }

    if (lrow == 0) {
#pragma unroll
        for (int s = 0; s < 2; ++s)
#pragma unroll
            for (int r = 0; r < 4; ++r) {
                int p = pbase + s * 16 + lgrp * 4 + r;
                unsigned w = b1[s][r];
                float d1 = __uint_as_float(w & 0xFFFFFE00u);
                float d2 = __uint_as_float(b2[s][r] & 0xFFFFFE00u);
                out_assign[p] = (float)(w & 0x1FFu);
                if (d2 - d1 <= MARGIN) {
                    int t = atomicAdd(&lcnt, 1);
                    llist[t] = p;
                }
            }
    }
    __syncthreads();
    int n = lcnt;
    if (tid == 0) lbase = n ? atomicAdd(gcnt, n) : 0;
    __syncthreads();
    for (int t = tid; t < n; t += 256) {
        int idx = lbase + t;
        if (idx < list_cap) glist[idx] = llist[t];
        else out_assign[llist[t]] = SENTINEL;   // ws too small: fallback fixes
    }
}

// Rescore v4: WAVE handles TWO points; lane l owns k = j*64+l (serial depth 8,
// not 512 -- kills R13/R15's 220-310us serial-chain floor). Centroids staged
// once per block in LDS as f32 rows at stride 68 (16B-aligned; bank window
// 4(k+q)%32 -> every bank touched exactly 8x per b128 = bandwidth floor, no
// pathological conflict). Per-lane GLOBAL rows (R12:780us, R14:352us) avoided.
// x rows wave-uniform -> s_loads. Dot = bit-exact R1 op sequence; argmin via
// proven packed (distbits<<32)|k 64-lane min (first-index-wins).
__global__ __launch_bounds__(256) void rescore_kernel(const float* __restrict__ x,
                                                      const float* __restrict__ c,
                                                      const float* __restrict__ csq,
                                                      const int* __restrict__ gcnt,
                                                      const int* __restrict__ glist,
                                                      int list_cap,
                                                      float* __restrict__ out_assign) {
    extern __shared__ char rsm[];
    float* cs = (float*)rsm;                       // [512][68] f32
    float* scsq = (float*)(rsm + KC * CSTRIDE * 4);// 512 f32

    int tid = threadIdx.x;
    int n = *gcnt;
    if (n > list_cap) n = list_cap;
    scsq[tid] = csq[tid];
    scsq[tid + 256] = csq[tid + 256];
#pragma unroll
    for (int it = 0; it < 32; ++it) {
        int idx = tid + it * 256;                  // 8192 float4 chunks
        int row = idx >> 4, q = idx & 15;
        float4 v = ((const float4*)(c + row * DD))[q];
        float* d = &cs[row * CSTRIDE + q * 4];
        d[0] = v.x; d[1] = v.y; d[2] = v.z; d[3] = v.w;
    }
    __syncthreads();
    if (n <= 0) return;

    int wid = tid >> 6, lane = tid & 63;
    int gw = blockIdx.x * 4 + wid;
    int stride2 = 256 * 4 * 2;

    for (int t0 = gw * 2; t0 < n; t0 += stride2) {
        int iA = __builtin_amdgcn_readfirstlane(glist[t0]);
        int t1 = (t0 + 1 < n) ? t0 + 1 : t0;
        int iB = __builtin_amdgcn_readfirstlane(glist[t1]);
        const float* xA = x + (size_t)iA * DD;     // wave-uniform -> s_loads
        const float* xB = x + (size_t)iB * DD;
        float xsqA = csq_pairwise8(xA);
        float xsqB = csq_pairwise8(xB);

        unsigned long long bA = ~0ull, bB = ~0ull;
#pragma unroll 1
        for (int j = 0; j < 8; ++j) {
            int k = j * 64 + lane;
            const float* crow = &cs[k * CSTRIDE];
            float a0 = 0.f, a1 = 0.f, a2 = 0.f, a3 = 0.f;
            float c0 = 0.f, c1 = 0.f, c2 = 0.f, c3 = 0.f;
#pragma unroll
            for (int q = 0; q < 16; ++q) {
                float4 cq = *(const float4*)(crow + q * 4);   // LDS b128
                a0 = __fmaf_rn(xA[4 * q + 0], cq.x, a0);
                a1 = __fmaf_rn(xA[4 * q + 1], cq.y, a1);
                a2 = __fmaf_rn(xA[4 * q + 2], cq.z, a2);
                a3 = __fmaf_rn(xA[4 * q + 3], cq.w, a3);
                c0 = __fmaf_rn(xB[4 * q + 0], cq.x, c0);
                c1 = __fmaf_rn(xB[4 * q + 1], cq.y, c1);
                c2 = __fmaf_rn(xB[4 * q + 2], cq.z, c2);
                c3 = __fmaf_rn(xB[4 * q + 3], cq.w, c3);
            }
            float sq = scsq[k];
            float accA = __fadd_rn(__fadd_rn(a0, a1), __fadd_rn(a2, a3));
            float accB = __fadd_rn(__fadd_rn(c0, c1), __fadd_rn(c2, c3));
            float dA = __fmaf_rn(-2.0f, accA, __fadd_rn(xsqA, sq));
            float dB = __fmaf_rn(-2.0f, accB, __fadd_rn(xsqB, sq));
            unsigned long long kA =
                ((unsigned long long)__float_as_uint(dA) << 32) | (unsigned)k;
            unsigned long long kB =
                ((unsigned long long)__float_as_uint(dB) << 32) | (unsigned)k;
            bA = bA < kA ? bA : kA;
            bB = bB < kB ? bB : kB;
        }
#pragma unroll
        for (int dd = 1; dd < 64; dd <<= 1) {
            unsigned hiA = (unsigned)__shfl_xor((int)(bA >> 32), dd);
            unsigned loA = (unsigned)__shfl_xor((int)(bA & 0xFFFFFFFFull), dd);
            unsigned long long oA = ((unsigned long long)hiA << 32) | loA;
            bA = bA < oA ? bA : oA;
            unsigned hiB = (unsigned)__shfl_xor((int)(bB >> 32), dd);
            unsigned loB = (unsigned)__shfl_xor((int)(bB & 0xFFFFFFFFull), dd);
            unsigned long long oB = ((unsigned long long)hiB << 32) | loB;
            bB = bB < oB ? bB : oB;
        }
        if (lane == 0) {
            out_assign[iA] = (float)(unsigned)(bA & 0xFFFFFFFFull);
            out_assign[iB] = (float)(unsigned)(bB & 0xFFFFFFFFull);
        }
    }
}

// Fallback: repairs any SENTINEL left by list overflow (normally zero work).
__global__ __launch_bounds__(256) void fallback_kernel(const float* __restrict__ x,
                                                       const float* __restrict__ c,
                                                       const float* __restrict__ csq,
                                                       float* __restrict__ out_assign) {
    int p = blockIdx.x * 256 + threadIdx.x;
    int lane = threadIdx.x & 63;
    float v = out_assign[p];
    unsigned long long mask = __ballot(v < 0.0f);
    int wbase = p & ~63;

    while (mask) {
        int b = __ffsll((long long)mask) - 1;
        mask &= mask - 1;
        int i = wbase + b;
        const float* xr = x + (size_t)i * DD;

        float x_sq = csq_pairwise8(xr);
        unsigned long long best = ~0ull;
#pragma unroll 1
        for (int j = 0; j < 8; ++j) {
            int k = j * 64 + lane;
            const float* crow = c + (size_t)k * DD;
            float a0 = 0.f, a1 = 0.f, a2 = 0.f, a3 = 0.f;
#pragma unroll
            for (int d = 0; d < DD; d += 4) {
                a0 = __fmaf_rn(xr[d + 0], crow[d + 0], a0);
                a1 = __fmaf_rn(xr[d + 1], crow[d + 1], a1);
                a2 = __fmaf_rn(xr[d + 2], crow[d + 2], a2);
                a3 = __fmaf_rn(xr[d + 3], crow[d + 3], a3);
            }
            float acc = __fadd_rn(__fadd_rn(a0, a1), __fadd_rn(a2, a3));
            float tt = __fadd_rn(x_sq, csq[k]);
            float dist = __fmaf_rn(-2.0f, acc, tt);
            unsigned long long key =
                ((unsigned long long)__float_as_uint(dist) << 32) | (unsigned)k;
            best = best < key ? best : key;
        }
#pragma unroll
        for (int dd = 1; dd < 64; dd <<= 1) {
            unsigned hi = (unsigned)__shfl_xor((int)(best >> 32), dd);
            unsigned lo = (unsigned)__shfl_xor((int)(best & 0xFFFFFFFFull), dd);
            unsigned long long o = ((unsigned long long)hi << 32) | lo;
            best = best < o ? best : o;
        }
        if (lane == 0) out_assign[i] = (float)(unsigned)(best & 0xFFFFFFFFull);
    }
}

extern "C" void kernel_launch(void* const* d_in, const int* in_sizes, int n_in,
                              void* d_out, int out_size, void* d_ws, size_t ws_size,
                              hipStream_t stream) {
    const float* x = (const float*)d_in[0];
    const float* c = (const float*)d_in[1];
    float* out = (float*)d_out;
    float* out_assign = out + KC * DD;

    char* ws = (char*)d_ws;
    int* gcnt = (int*)(ws + WS_GCNT);
    float* cs16 = (float*)(ws + WS_CS16);
    float* csq = (float*)(ws + WS_CSQ);
    _Float16* cf16 = (_Float16*)(ws + WS_CF16);
    int* glist = (int*)(ws + WS_LIST);
    int list_cap = 0;
    if (ws_size > WS_LIST + 4) {
        size_t cap = (ws_size - WS_LIST) / 4;
        list_cap = cap > NPTS ? NPTS : (int)cap;
    }

    hipMemsetAsync(gcnt, 0, 16, stream);
    prep_kernel<<<(KC * DD + 255) / 256, 256, 0, stream>>>(c, out, cf16, cs16, csq);
    approx_kernel<<<NPTS / 128, 256, 67584, stream>>>(x, cf16, cs16, out_assign,
                                                      gcnt, glist, list_cap);
    rescore_kernel<<<256, 256, KC * CSTRIDE * 4 + 2048, stream>>>(
        x, c, csq, gcnt, glist, list_cap, out_assign);
    fallback_kernel<<<NPTS / 256, 256, 0, stream>>>(x, c, csq, out_assign);
}

// Round 17
// 158.672 us; speedup vs baseline: 2.9944x; 1.2291x over previous
//
#include <hip/hip_runtime.h>
#include <math.h>

#define NPTS 262144
#define KC 512
#define DD 64
#define MARGIN 0.02f
#define SHIFT 32.0f
#define SENTINEL -1.0f
#define CSTRIDE 68            // f32 row stride in LDS for rescore
#define TILES 4               // point-tiles per approx block

typedef _Float16 f16x8 __attribute__((ext_vector_type(8)));
typedef float f32x4 __attribute__((ext_vector_type(4)));

// ws layout (bytes)
#define WS_GCNT  0      // int global list counter (memset each launch)
#define WS_CS16  16     // 512 f32: c_sq + SHIFT
#define WS_CSQ   2064   // 512 f32: exact c_sq (pairwise-8)
#define WS_CF16  4112   // 512*64 f16 centroids (65536 B)
#define WS_LIST  69648  // compact flagged-point list (ws-size-guarded)

__device__ __forceinline__ float csq_pairwise8(const float* row) {
    float r[8];
#pragma unroll
    for (int t = 0; t < 8; ++t) r[t] = __fmul_rn(row[t], row[t]);
#pragma unroll
    for (int b = 1; b < 8; ++b)
#pragma unroll
        for (int t = 0; t < 8; ++t)
            r[t] = __fadd_rn(r[t], __fmul_rn(row[8 * b + t], row[8 * b + t]));
    return __fadd_rn(__fadd_rn(__fadd_rn(r[0], r[1]), __fadd_rn(r[2], r[3])),
                     __fadd_rn(__fadd_rn(r[4], r[5]), __fadd_rn(r[6], r[7])));
}

__global__ __launch_bounds__(256) void prep_kernel(const float* __restrict__ c,
                                                   float* __restrict__ out_c,
                                                   _Float16* __restrict__ cf16,
                                                   float* __restrict__ cs16,
                                                   float* __restrict__ csq) {
    int j = blockIdx.x * 256 + threadIdx.x;
    if (j < KC * DD) {
        float v = c[j];
        out_c[j] = v;
        cf16[j] = (_Float16)v;  // RNE
    }
    if (j < KC) {
        float s = csq_pairwise8(c + j * DD);
        csq[j] = s;
        cs16[j] = s + SHIFT;
    }
}

// R16's clean approx kernel + PERSISTENT TILES: stage the 64 KB centroid tile
// ONCE, then compute TILES=4 point-tiles of 128 against it (R16: 2048 blocks
// each staged 64 KB to compute 128 points -> staging-dominated, 125us with
// MfmaUtil 5%). Inner tile body is byte-identical to the proven R16 code.
__global__ __launch_bounds__(256, 2) void approx_kernel(const float* __restrict__ x,
                                                        const _Float16* __restrict__ cf16,
                                                        const float* __restrict__ cs16g,
                                                        float* __restrict__ out_assign,
                                                        int* __restrict__ gcnt,
                                                        int* __restrict__ glist,
                                                        int list_cap) {
    extern __shared__ char smem[];          // [0,64K): swizzled c_f16
    float* scs = (float*)(smem + 65536);    // 512 f32: c_sq + SHIFT
    __shared__ int llist[128];
    __shared__ int lcnt, lbase;

    int tid = threadIdx.x;
    const uint4* src = (const uint4*)cf16;
#pragma unroll
    for (int i = 0; i < 16; ++i) {
        int chunk = tid + i * 256;          // 4096 chunks of 16B
        int row = chunk >> 3, slot = chunk & 7;
        uint4 v = src[chunk];
        *(uint4*)(smem + row * 128 + ((slot ^ (row & 7)) << 4)) = v;
    }
    scs[tid] = cs16g[tid];
    scs[tid + 256] = cs16g[tid + 256];

    int wid = tid >> 6, lane = tid & 63;
    int lrow = lane & 15, lgrp = lane >> 4;

    for (int tile = 0; tile < TILES; ++tile) {
        __syncthreads();   // staging done (tile 0) / prior tile compaction done
        if (tid == 0) lcnt = 0;
        int pbase = (blockIdx.x * TILES + tile) * 128 + wid * 32;

        // A-frags (layout proven absmax=0 R4-R16).
        f16x8 a[2][2];
#pragma unroll
        for (int s = 0; s < 2; ++s)
#pragma unroll
            for (int kk = 0; kk < 2; ++kk) {
                const float4* p = (const float4*)(x + (size_t)(pbase + s * 16 + lrow) * DD
                                                  + kk * 32 + lgrp * 8);
                float4 u0 = p[0], u1 = p[1];
                f16x8 t;
                t[0] = (_Float16)u0.x; t[1] = (_Float16)u0.y;
                t[2] = (_Float16)u0.z; t[3] = (_Float16)u0.w;
                t[4] = (_Float16)u1.x; t[5] = (_Float16)u1.y;
                t[6] = (_Float16)u1.z; t[7] = (_Float16)u1.w;
                a[s][kk] = t;
            }

        unsigned b1[2][4], b2[2][4];
#pragma unroll
        for (int s = 0; s < 2; ++s)
#pragma unroll
            for (int r = 0; r < 4; ++r) { b1[s][r] = 0xFFFFFFFFu; b2[s][r] = 0xFFFFFFFFu; }

        int base0 = lrow * 128 + ((lgrp ^ (lane & 7)) << 4);
        int base1 = base0 ^ 64;
        int centv = lrow;

        for (int ct = 0; ct < 32; ++ct) {
            f16x8 bk0 = *(const f16x8*)(smem + base0);
            f16x8 bk1 = *(const f16x8*)(smem + base1);
            float cs = scs[centv];
            f32x4 acc0 = {0.f, 0.f, 0.f, 0.f}, acc1 = {0.f, 0.f, 0.f, 0.f};
            acc0 = __builtin_amdgcn_mfma_f32_16x16x32_f16(a[0][0], bk0, acc0, 0, 0, 0);
            acc0 = __builtin_amdgcn_mfma_f32_16x16x32_f16(a[0][1], bk1, acc0, 0, 0, 0);
            acc1 = __builtin_amdgcn_mfma_f32_16x16x32_f16(a[1][0], bk0, acc1, 0, 0, 0);
            acc1 = __builtin_amdgcn_mfma_f32_16x16x32_f16(a[1][1], bk1, acc1, 0, 0, 0);
#pragma unroll
            for (int r = 0; r < 4; ++r) {
                float d0 = __builtin_fmaf(-2.0f, acc0[r], cs);
                float d1 = __builtin_fmaf(-2.0f, acc1[r], cs);
                unsigned k0 = (__float_as_uint(d0) & 0xFFFFFE00u) | (unsigned)centv;
                unsigned k1 = (__float_as_uint(d1) & 0xFFFFFE00u) | (unsigned)centv;
                unsigned m0 = max(b1[0][r], k0);
                b1[0][r] = min(b1[0][r], k0);
                b2[0][r] = min(b2[0][r], m0);
                unsigned m1 = max(b1[1][r], k1);
                b1[1][r] = min(b1[1][r], k1);
                b2[1][r] = min(b2[1][r], m1);
            }
            base0 += 2048; base1 += 2048; centv += 16;
        }

#pragma unroll
        for (int d = 1; d < 16; d <<= 1) {
#pragma unroll
            for (int s = 0; s < 2; ++s)
#pragma unroll
                for (int r = 0; r < 4; ++r) {
                    unsigned o1 = (unsigned)__shfl_xor((int)b1[s][r], d);
                    unsigned o2 = (unsigned)__shfl_xor((int)b2[s][r], d);
                    unsigned mx = max(b1[s][r], o1);
                    b1[s][r] = min(b1[s][r], o1);
                    b2[s][r] = min(min(b2[s][r], o2), mx);
                }
        }

        __syncthreads();   // lcnt reset visible to all before flag atomics
        if (lrow == 0) {
#pragma unroll
            for (int s = 0; s < 2; ++s)
#pragma unroll
                for (int r = 0; r < 4; ++r) {
                    int p = pbase + s * 16 + lgrp * 4 + r;
                    unsigned w = b1[s][r];
                    float d1 = __uint_as_float(w & 0xFFFFFE00u);
                    float d2 = __uint_as_float(b2[s][r] & 0xFFFFFE00u);
                    out_assign[p] = (float)(w & 0x1FFu);
                    if (d2 - d1 <= MARGIN) {
                        int t = atomicAdd(&lcnt, 1);
                        llist[t] = p;
                    }
                }
        }
        __syncthreads();   // flags complete
        int n = lcnt;
        if (tid == 0) lbase = n ? atomicAdd(gcnt, n) : 0;
        __syncthreads();   // lbase visible
        for (int t = tid; t < n; t += 256) {
            int idx = lbase + t;
            if (idx < list_cap) glist[idx] = llist[t];
            else out_assign[llist[t]] = SENTINEL;   // ws too small: fallback fixes
        }
    }
}

// Rescore v4 (R16-proven, byte-identical): wave per 2 points, lane-split k
// from LDS-staged f32 centroids, wave-uniform x -> s_loads.
__global__ __launch_bounds__(256) void rescore_kernel(const float* __restrict__ x,
                                                      const float* __restrict__ c,
                                                      const float* __restrict__ csq,
                                                      const int* __restrict__ gcnt,
                                                      const int* __restrict__ glist,
                                                      int list_cap,
                                                      float* __restrict__ out_assign) {
    extern __shared__ char rsm[];
    float* cs = (float*)rsm;                       // [512][68] f32
    float* scsq = (float*)(rsm + KC * CSTRIDE * 4);// 512 f32

    int tid = threadIdx.x;
    int n = *gcnt;
    if (n > list_cap) n = list_cap;
    scsq[tid] = csq[tid];
    scsq[tid + 256] = csq[tid + 256];
#pragma unroll
    for (int it = 0; it < 32; ++it) {
        int idx = tid + it * 256;                  // 8192 float4 chunks
        int row = idx >> 4, q = idx & 15;
        float4 v = ((const float4*)(c + row * DD))[q];
        float* d = &cs[row * CSTRIDE + q * 4];
        d[0] = v.x; d[1] = v.y; d[2] = v.z; d[3] = v.w;
    }
    __syncthreads();
    if (n <= 0) return;

    int wid = tid >> 6, lane = tid & 63;
    int gw = blockIdx.x * 4 + wid;
    int stride2 = 256 * 4 * 2;

    for (int t0 = gw * 2; t0 < n; t0 += stride2) {
        int iA = __builtin_amdgcn_readfirstlane(glist[t0]);
        int t1 = (t0 + 1 < n) ? t0 + 1 : t0;
        int iB = __builtin_amdgcn_readfirstlane(glist[t1]);
        const float* xA = x + (size_t)iA * DD;     // wave-uniform -> s_loads
        const float* xB = x + (size_t)iB * DD;
        float xsqA = csq_pairwise8(xA);
        float xsqB = csq_pairwise8(xB);

        unsigned long long bA = ~0ull, bB = ~0ull;
#pragma unroll 1
        for (int j = 0; j < 8; ++j) {
            int k = j * 64 + lane;
            const float* crow = &cs[k * CSTRIDE];
            float a0 = 0.f, a1 = 0.f, a2 = 0.f, a3 = 0.f;
            float c0 = 0.f, c1 = 0.f, c2 = 0.f, c3 = 0.f;
#pragma unroll
            for (int q = 0; q < 16; ++q) {
                float4 cq = *(const float4*)(crow + q * 4);   // LDS b128
                a0 = __fmaf_rn(xA[4 * q + 0], cq.x, a0);
                a1 = __fmaf_rn(xA[4 * q + 1], cq.y, a1);
                a2 = __fmaf_rn(xA[4 * q + 2], cq.z, a2);
                a3 = __fmaf_rn(xA[4 * q + 3], cq.w, a3);
                c0 = __fmaf_rn(xB[4 * q + 0], cq.x, c0);
                c1 = __fmaf_rn(xB[4 * q + 1], cq.y, c1);
                c2 = __fmaf_rn(xB[4 * q + 2], cq.z, c2);
                c3 = __fmaf_rn(xB[4 * q + 3], cq.w, c3);
            }
            float sq = scsq[k];
            float accA = __fadd_rn(__fadd_rn(a0, a1), __fadd_rn(a2, a3));
            float accB = __fadd_rn(__fadd_rn(c0, c1), __fadd_rn(c2, c3));
            float dA = __fmaf_rn(-2.0f, accA, __fadd_rn(xsqA, sq));
            float dB = __fmaf_rn(-2.0f, accB, __fadd_rn(xsqB, sq));
            unsigned long long kA =
                ((unsigned long long)__float_as_uint(dA) << 32) | (unsigned)k;
            unsigned long long kB =
                ((unsigned long long)__float_as_uint(dB) << 32) | (unsigned)k;
            bA = bA < kA ? bA : kA;
            bB = bB < kB ? bB : kB;
        }
#pragma unroll
        for (int dd = 1; dd < 64; dd <<= 1) {
            unsigned hiA = (unsigned)__shfl_xor((int)(bA >> 32), dd);
            unsigned loA = (unsigned)__shfl_xor((int)(bA & 0xFFFFFFFFull), dd);
            unsigned long long oA = ((unsigned long long)hiA << 32) | loA;
            bA = bA < oA ? bA : oA;
            unsigned hiB = (unsigned)__shfl_xor((int)(bB >> 32), dd);
            unsigned loB = (unsigned)__shfl_xor((int)(bB & 0xFFFFFFFFull), dd);
            unsigned long long oB = ((unsigned long long)hiB << 32) | loB;
            bB = bB < oB ? bB : oB;
        }
        if (lane == 0) {
            out_assign[iA] = (float)(unsigned)(bA & 0xFFFFFFFFull);
            out_assign[iB] = (float)(unsigned)(bB & 0xFFFFFFFFull);
        }
    }
}

// Fallback: repairs any SENTINEL left by list overflow (normally zero work).
__global__ __launch_bounds__(256) void fallback_kernel(const float* __restrict__ x,
                                                       const float* __restrict__ c,
                                                       const float* __restrict__ csq,
                                                       float* __restrict__ out_assign) {
    int p = blockIdx.x * 256 + threadIdx.x;
    int lane = threadIdx.x & 63;
    float v = out_assign[p];
    unsigned long long mask = __ballot(v < 0.0f);
    int wbase = p & ~63;

    while (mask) {
        int b = __ffsll((long long)mask) - 1;
        mask &= mask - 1;
        int i = wbase + b;
        const float* xr = x + (size_t)i * DD;

        float x_sq = csq_pairwise8(xr);
        unsigned long long best = ~0ull;
#pragma unroll 1
        for (int j = 0; j < 8; ++j) {
            int k = j * 64 + lane;
            const float* crow = c + (size_t)k * DD;
            float a0 = 0.f, a1 = 0.f, a2 = 0.f, a3 = 0.f;
#pragma unroll
            for (int d = 0; d < DD; d += 4) {
                a0 = __fmaf_rn(xr[d + 0], crow[d + 0], a0);
                a1 = __fmaf_rn(xr[d + 1], crow[d + 1], a1);
                a2 = __fmaf_rn(xr[d + 2], crow[d + 2], a2);
                a3 = __fmaf_rn(xr[d + 3], crow[d + 3], a3);
            }
            float acc = __fadd_rn(__fadd_rn(a0, a1), __fadd_rn(a2, a3));
            float tt = __fadd_rn(x_sq, csq[k]);
            float dist = __fmaf_rn(-2.0f, acc, tt);
            unsigned long long key =
                ((unsigned long long)__float_as_uint(dist) << 32) | (unsigned)k;
            best = best < key ? best : key;
        }
#pragma unroll
        for (int dd = 1; dd < 64; dd <<= 1) {
            unsigned hi = (unsigned)__shfl_xor((int)(best >> 32), dd);
            unsigned lo = (unsigned)__shfl_xor((int)(best & 0xFFFFFFFFull), dd);
            unsigned long long o = ((unsigned long long)hi << 32) | lo;
            best = best < o ? best : o;
        }
        if (lane == 0) out_assign[i] = (float)(unsigned)(best & 0xFFFFFFFFull);
    }
}

extern "C" void kernel_launch(void* const* d_in, const int* in_sizes, int n_in,
                              void* d_out, int out_size, void* d_ws, size_t ws_size,
                              hipStream_t stream) {
    const float* x = (const float*)d_in[0];
    const float* c = (const float*)d_in[1];
    float* out = (float*)d_out;
    float* out_assign = out + KC * DD;

    char* ws = (char*)d_ws;
    int* gcnt = (int*)(ws + WS_GCNT);
    float* cs16 = (float*)(ws + WS_CS16);
    float* csq = (float*)(ws + WS_CSQ);
    _Float16* cf16 = (_Float16*)(ws + WS_CF16);
    int* glist = (int*)(ws + WS_LIST);
    int list_cap = 0;
    if (ws_size > WS_LIST + 4) {
        size_t cap = (ws_size - WS_LIST) / 4;
        list_cap = cap > NPTS ? NPTS : (int)cap;
    }

    hipMemsetAsync(gcnt, 0, 16, stream);
    prep_kernel<<<(KC * DD + 255) / 256, 256, 0, stream>>>(c, out, cf16, cs16, csq);
    approx_kernel<<<NPTS / (128 * TILES), 256, 67584, stream>>>(
        x, cf16, cs16, out_assign, gcnt, glist, list_cap);
    rescore_kernel<<<256, 256, KC * CSTRIDE * 4 + 2048, stream>>>(
        x, c, csq, gcnt, glist, list_cap, out_assign);
    fallback_kernel<<<NPTS / 256, 256, 0, stream>>>(x, c, csq, out_assign);
}

// Round 18
// 158.530 us; speedup vs baseline: 2.9971x; 1.0009x over previous
//
#include <hip/hip_runtime.h>
#include <math.h>

#define NPTS 262144
#define KC 512
#define DD 64
#define MARGIN 0.02f
#define SHIFT 32.0f
#define SENTINEL -1.0f
#define CSTRIDE 68            // f32 row stride in LDS for rescore
#define TILES 4               // point-tiles per approx block

typedef _Float16 f16x8 __attribute__((ext_vector_type(8)));
typedef float f32x4 __attribute__((ext_vector_type(4)));

// ws layout (bytes)
#define WS_GCNT  0      // int[4]: [0] list counter, [1] overflow count (memset)
#define WS_CS16  16     // 512 f32: c_sq + SHIFT
#define WS_CSQ   2064   // 512 f32: exact c_sq (pairwise-8)
#define WS_CF16  4112   // 512*64 f16 centroids (65536 B)
#define WS_LIST  69648  // compact flagged-point list (ws-size-guarded)

__device__ __forceinline__ float csq_pairwise8(const float* row) {
    float r[8];
#pragma unroll
    for (int t = 0; t < 8; ++t) r[t] = __fmul_rn(row[t], row[t]);
#pragma unroll
    for (int b = 1; b < 8; ++b)
#pragma unroll
        for (int t = 0; t < 8; ++t)
            r[t] = __fadd_rn(r[t], __fmul_rn(row[8 * b + t], row[8 * b + t]));
    return __fadd_rn(__fadd_rn(__fadd_rn(r[0], r[1]), __fadd_rn(r[2], r[3])),
                     __fadd_rn(__fadd_rn(r[4], r[5]), __fadd_rn(r[6], r[7])));
}

__global__ __launch_bounds__(256) void prep_kernel(const float* __restrict__ c,
                                                   float* __restrict__ out_c,
                                                   _Float16* __restrict__ cf16,
                                                   float* __restrict__ cs16,
                                                   float* __restrict__ csq) {
    int j = blockIdx.x * 256 + threadIdx.x;
    if (j < KC * DD) {
        float v = c[j];
        out_c[j] = v;
        cf16[j] = (_Float16)v;  // RNE
    }
    if (j < KC) {
        float s = csq_pairwise8(c + j * DD);
        csq[j] = s;
        cs16[j] = s + SHIFT;
    }
}

// R17's persistent-tile approx kernel (clean: VGPR=40, WRITE 1.2MB) with the
// ct-loop unrolled 2x: at 2 waves/SIMD the per-iter chain LDS->MFMA->VALU is
// latency-exposed (R17: MfmaUtil 7.8%, VALUBusy 28%, nothing >25% loaded);
// two iterations in flight overlap the chains. Lean state preserved.
__global__ __launch_bounds__(256, 2) void approx_kernel(const float* __restrict__ x,
                                                        const _Float16* __restrict__ cf16,
                                                        const float* __restrict__ cs16g,
                                                        float* __restrict__ out_assign,
                                                        int* __restrict__ gcnt,
                                                        int* __restrict__ glist,
                                                        int list_cap) {
    extern __shared__ char smem[];          // [0,64K): swizzled c_f16
    float* scs = (float*)(smem + 65536);    // 512 f32: c_sq + SHIFT
    __shared__ int llist[128];
    __shared__ int lcnt, lbase;

    int tid = threadIdx.x;
    const uint4* src = (const uint4*)cf16;
#pragma unroll
    for (int i = 0; i < 16; ++i) {
        int chunk = tid + i * 256;          // 4096 chunks of 16B
        int row = chunk >> 3, slot = chunk & 7;
        uint4 v = src[chunk];
        *(uint4*)(smem + row * 128 + ((slot ^ (row & 7)) << 4)) = v;
    }
    scs[tid] = cs16g[tid];
    scs[tid + 256] = cs16g[tid + 256];

    int wid = tid >> 6, lane = tid & 63;
    int lrow = lane & 15, lgrp = lane >> 4;

    for (int tile = 0; tile < TILES; ++tile) {
        __syncthreads();   // staging done (tile 0) / prior tile compaction done
        if (tid == 0) lcnt = 0;
        int pbase = (blockIdx.x * TILES + tile) * 128 + wid * 32;

        // A-frags (layout proven absmax=0 R4-R17).
        f16x8 a[2][2];
#pragma unroll
        for (int s = 0; s < 2; ++s)
#pragma unroll
            for (int kk = 0; kk < 2; ++kk) {
                const float4* p = (const float4*)(x + (size_t)(pbase + s * 16 + lrow) * DD
                                                  + kk * 32 + lgrp * 8);
                float4 u0 = p[0], u1 = p[1];
                f16x8 t;
                t[0] = (_Float16)u0.x; t[1] = (_Float16)u0.y;
                t[2] = (_Float16)u0.z; t[3] = (_Float16)u0.w;
                t[4] = (_Float16)u1.x; t[5] = (_Float16)u1.y;
                t[6] = (_Float16)u1.z; t[7] = (_Float16)u1.w;
                a[s][kk] = t;
            }

        unsigned b1[2][4], b2[2][4];
#pragma unroll
        for (int s = 0; s < 2; ++s)
#pragma unroll
            for (int r = 0; r < 4; ++r) { b1[s][r] = 0xFFFFFFFFu; b2[s][r] = 0xFFFFFFFFu; }

        int base0 = lrow * 128 + ((lgrp ^ (lane & 7)) << 4);
        int base1 = base0 ^ 64;
        int centv = lrow;

#pragma unroll 2
        for (int ct = 0; ct < 32; ++ct) {
            f16x8 bk0 = *(const f16x8*)(smem + base0);
            f16x8 bk1 = *(const f16x8*)(smem + base1);
            float cs = scs[centv];
            f32x4 acc0 = {0.f, 0.f, 0.f, 0.f}, acc1 = {0.f, 0.f, 0.f, 0.f};
            acc0 = __builtin_amdgcn_mfma_f32_16x16x32_f16(a[0][0], bk0, acc0, 0, 0, 0);
            acc0 = __builtin_amdgcn_mfma_f32_16x16x32_f16(a[0][1], bk1, acc0, 0, 0, 0);
            acc1 = __builtin_amdgcn_mfma_f32_16x16x32_f16(a[1][0], bk0, acc1, 0, 0, 0);
            acc1 = __builtin_amdgcn_mfma_f32_16x16x32_f16(a[1][1], bk1, acc1, 0, 0, 0);
#pragma unroll
            for (int r = 0; r < 4; ++r) {
                float d0 = __builtin_fmaf(-2.0f, acc0[r], cs);
                float d1 = __builtin_fmaf(-2.0f, acc1[r], cs);
                unsigned k0 = (__float_as_uint(d0) & 0xFFFFFE00u) | (unsigned)centv;
                unsigned k1 = (__float_as_uint(d1) & 0xFFFFFE00u) | (unsigned)centv;
                unsigned m0 = max(b1[0][r], k0);
                b1[0][r] = min(b1[0][r], k0);
                b2[0][r] = min(b2[0][r], m0);
                unsigned m1 = max(b1[1][r], k1);
                b1[1][r] = min(b1[1][r], k1);
                b2[1][r] = min(b2[1][r], m1);
            }
            base0 += 2048; base1 += 2048; centv += 16;
        }

#pragma unroll
        for (int d = 1; d < 16; d <<= 1) {
#pragma unroll
            for (int s = 0; s < 2; ++s)
#pragma unroll
                for (int r = 0; r < 4; ++r) {
                    unsigned o1 = (unsigned)__shfl_xor((int)b1[s][r], d);
                    unsigned o2 = (unsigned)__shfl_xor((int)b2[s][r], d);
                    unsigned mx = max(b1[s][r], o1);
                    b1[s][r] = min(b1[s][r], o1);
                    b2[s][r] = min(min(b2[s][r], o2), mx);
                }
        }

        __syncthreads();   // lcnt reset visible to all before flag atomics
        if (lrow == 0) {
#pragma unroll
            for (int s = 0; s < 2; ++s)
#pragma unroll
                for (int r = 0; r < 4; ++r) {
                    int p = pbase + s * 16 + lgrp * 4 + r;
                    unsigned w = b1[s][r];
                    float d1 = __uint_as_float(w & 0xFFFFFE00u);
                    float d2 = __uint_as_float(b2[s][r] & 0xFFFFFE00u);
                    out_assign[p] = (float)(w & 0x1FFu);
                    if (d2 - d1 <= MARGIN) {
                        int t = atomicAdd(&lcnt, 1);
                        llist[t] = p;
                    }
                }
        }
        __syncthreads();   // flags complete
        int n = lcnt;
        if (tid == 0) lbase = n ? atomicAdd(gcnt, n) : 0;
        __syncthreads();   // lbase visible
        for (int t = tid; t < n; t += 256) {
            int idx = lbase + t;
            if (idx < list_cap) glist[idx] = llist[t];
            else {
                out_assign[llist[t]] = SENTINEL;   // ws too small: fallback fixes
                atomicAdd(gcnt + 1, 1);            // overflow count (rare)
            }
        }
    }
}

// Rescore (R16/R17-proven, byte-identical): wave per 2 points, lane-split k
// from LDS-staged f32 centroids, wave-uniform x -> s_loads.
__global__ __launch_bounds__(256) void rescore_kernel(const float* __restrict__ x,
                                                      const float* __restrict__ c,
                                                      const float* __restrict__ csq,
                                                      const int* __restrict__ gcnt,
                                                      const int* __restrict__ glist,
                                                      int list_cap,
                                                      float* __restrict__ out_assign) {
    extern __shared__ char rsm[];
    float* cs = (float*)rsm;                       // [512][68] f32
    float* scsq = (float*)(rsm + KC * CSTRIDE * 4);// 512 f32

    int tid = threadIdx.x;
    int n = *gcnt;
    if (n > list_cap) n = list_cap;
    scsq[tid] = csq[tid];
    scsq[tid + 256] = csq[tid + 256];
#pragma unroll
    for (int it = 0; it < 32; ++it) {
        int idx = tid + it * 256;                  // 8192 float4 chunks
        int row = idx >> 4, q = idx & 15;
        float4 v = ((const float4*)(c + row * DD))[q];
        float* d = &cs[row * CSTRIDE + q * 4];
        d[0] = v.x; d[1] = v.y; d[2] = v.z; d[3] = v.w;
    }
    __syncthreads();
    if (n <= 0) return;

    int wid = tid >> 6, lane = tid & 63;
    int gw = blockIdx.x * 4 + wid;
    int stride2 = 256 * 4 * 2;

    for (int t0 = gw * 2; t0 < n; t0 += stride2) {
        int iA = __builtin_amdgcn_readfirstlane(glist[t0]);
        int t1 = (t0 + 1 < n) ? t0 + 1 : t0;
        int iB = __builtin_amdgcn_readfirstlane(glist[t1]);
        const float* xA = x + (size_t)iA * DD;     // wave-uniform -> s_loads
        const float* xB = x + (size_t)iB * DD;
        float xsqA = csq_pairwise8(xA);
        float xsqB = csq_pairwise8(xB);

        unsigned long long bA = ~0ull, bB = ~0ull;
#pragma unroll 1
        for (int j = 0; j < 8; ++j) {
            int k = j * 64 + lane;
            const float* crow = &cs[k * CSTRIDE];
            float a0 = 0.f, a1 = 0.f, a2 = 0.f, a3 = 0.f;
            float c0 = 0.f, c1 = 0.f, c2 = 0.f, c3 = 0.f;
#pragma unroll
            for (int q = 0; q < 16; ++q) {
                float4 cq = *(const float4*)(crow + q * 4);   // LDS b128
                a0 = __fmaf_rn(xA[4 * q + 0], cq.x, a0);
                a1 = __fmaf_rn(xA[4 * q + 1], cq.y, a1);
                a2 = __fmaf_rn(xA[4 * q + 2], cq.z, a2);
                a3 = __fmaf_rn(xA[4 * q + 3], cq.w, a3);
                c0 = __fmaf_rn(xB[4 * q + 0], cq.x, c0);
                c1 = __fmaf_rn(xB[4 * q + 1], cq.y, c1);
                c2 = __fmaf_rn(xB[4 * q + 2], cq.z, c2);
                c3 = __fmaf_rn(xB[4 * q + 3], cq.w, c3);
            }
            float sq = scsq[k];
            float accA = __fadd_rn(__fadd_rn(a0, a1), __fadd_rn(a2, a3));
            float accB = __fadd_rn(__fadd_rn(c0, c1), __fadd_rn(c2, c3));
            float dA = __fmaf_rn(-2.0f, accA, __fadd_rn(xsqA, sq));
            float dB = __fmaf_rn(-2.0f, accB, __fadd_rn(xsqB, sq));
            unsigned long long kA =
                ((unsigned long long)__float_as_uint(dA) << 32) | (unsigned)k;
            unsigned long long kB =
                ((unsigned long long)__float_as_uint(dB) << 32) | (unsigned)k;
            bA = bA < kA ? bA : kA;
            bB = bB < kB ? bB : kB;
        }
#pragma unroll
        for (int dd = 1; dd < 64; dd <<= 1) {
            unsigned hiA = (unsigned)__shfl_xor((int)(bA >> 32), dd);
            unsigned loA = (unsigned)__shfl_xor((int)(bA & 0xFFFFFFFFull), dd);
            unsigned long long oA = ((unsigned long long)hiA << 32) | loA;
            bA = bA < oA ? bA : oA;
            unsigned hiB = (unsigned)__shfl_xor((int)(bB >> 32), dd);
            unsigned loB = (unsigned)__shfl_xor((int)(bB & 0xFFFFFFFFull), dd);
            unsigned long long oB = ((unsigned long long)hiB << 32) | loB;
            bB = bB < oB ? bB : oB;
        }
        if (lane == 0) {
            out_assign[iA] = (float)(unsigned)(bA & 0xFFFFFFFFull);
            out_assign[iB] = (float)(unsigned)(bB & 0xFFFFFFFFull);
        }
    }
}

// Fallback: only runs if the compact list overflowed (gcnt[1] > 0 -- normally
// zero, so every block exits after one cached scalar read).
__global__ __launch_bounds__(256) void fallback_kernel(const float* __restrict__ x,
                                                       const float* __restrict__ c,
                                                       const float* __restrict__ csq,
                                                       const int* __restrict__ gcnt,
                                                       float* __restrict__ out_assign) {
    if (gcnt[1] == 0) return;               // no overflow: launch-overhead only
    int p = blockIdx.x * 256 + threadIdx.x;
    int lane = threadIdx.x & 63;
    float v = out_assign[p];
    unsigned long long mask = __ballot(v < 0.0f);
    int wbase = p & ~63;

    while (mask) {
        int b = __ffsll((long long)mask) - 1;
        mask &= mask - 1;
        int i = wbase + b;
        const float* xr = x + (size_t)i * DD;

        float x_sq = csq_pairwise8(xr);
        unsigned long long best = ~0ull;
#pragma unroll 1
        for (int j = 0; j < 8; ++j) {
            int k = j * 64 + lane;
            const float* crow = c + (size_t)k * DD;
            float a0 = 0.f, a1 = 0.f, a2 = 0.f, a3 = 0.f;
#pragma unroll
            for (int d = 0; d < DD; d += 4) {
                a0 = __fmaf_rn(xr[d + 0], crow[d + 0], a0);
                a1 = __fmaf_rn(xr[d + 1], crow[d + 1], a1);
                a2 = __fmaf_rn(xr[d + 2], crow[d + 2], a2);
                a3 = __fmaf_rn(xr[d + 3], crow[d + 3], a3);
            }
            float acc = __fadd_rn(__fadd_rn(a0, a1), __fadd_rn(a2, a3));
            float tt = __fadd_rn(x_sq, csq[k]);
            float dist = __fmaf_rn(-2.0f, acc, tt);
            unsigned long long key =
                ((unsigned long long)__float_as_uint(dist) << 32) | (unsigned)k;
            best = best < key ? best : key;
        }
#pragma unroll
        for (int dd = 1; dd < 64; dd <<= 1) {
            unsigned hi = (unsigned)__shfl_xor((int)(best >> 32), dd);
            unsigned lo = (unsigned)__shfl_xor((int)(best & 0xFFFFFFFFull), dd);
            unsigned long long o = ((unsigned long long)hi << 32) | lo;
            best = best < o ? best : o;
        }
        if (lane == 0) out_assign[i] = (float)(unsigned)(best & 0xFFFFFFFFull);
    }
}

extern "C" void kernel_launch(void* const* d_in, const int* in_sizes, int n_in,
                              void* d_out, int out_size, void* d_ws, size_t ws_size,
                              hipStream_t stream) {
    const float* x = (const float*)d_in[0];
    const float* c = (const float*)d_in[1];
    float* out = (float*)d_out;
    float* out_assign = out + KC * DD;

    char* ws = (char*)d_ws;
    int* gcnt = (int*)(ws + WS_GCNT);
    float* cs16 = (float*)(ws + WS_CS16);
    float* csq = (float*)(ws + WS_CSQ);
    _Float16* cf16 = (_Float16*)(ws + WS_CF16);
    int* glist = (int*)(ws + WS_LIST);
    int list_cap = 0;
    if (ws_size > WS_LIST + 4) {
        size_t cap = (ws_size - WS_LIST) / 4;
        list_cap = cap > NPTS ? NPTS : (int)cap;
    }

    hipMemsetAsync(gcnt, 0, 16, stream);
    prep_kernel<<<(KC * DD + 255) / 256, 256, 0, stream>>>(c, out, cf16, cs16, csq);
    approx_kernel<<<NPTS / (128 * TILES), 256, 67584, stream>>>(
        x, cf16, cs16, out_assign, gcnt, glist, list_cap);
    rescore_kernel<<<256, 256, KC * CSTRIDE * 4 + 2048, stream>>>(
        x, c, csq, gcnt, glist, list_cap, out_assign);
    fallback_kernel<<<NPTS / 256, 256, 0, stream>>>(x, c, csq, gcnt, out_assign);
}

// Round 19
// 155.829 us; speedup vs baseline: 3.0490x; 1.0173x over previous
//
#include <hip/hip_runtime.h>
#include <math.h>

#define NPTS 262144
#define KC 512
#define DD 64
#define MARGIN 0.02f
#define SHIFT 32.0f
#define SENTINEL -1.0f
#define CSTRIDE 68            // f32 row stride in LDS for rescore
#define ABLOCK 512            // approx block: 8 waves -> 4 waves/SIMD at 2 blocks/CU
#define TILES 2               // 256-point tiles per approx block

typedef _Float16 f16x8 __attribute__((ext_vector_type(8)));
typedef float f32x4 __attribute__((ext_vector_type(4)));

// ws layout (bytes)
#define WS_GCNT  0      // int[4]: [0] list counter, [1] overflow count (memset)
#define WS_CS16  16     // 512 f32: c_sq + SHIFT
#define WS_CSQ   2064   // 512 f32: exact c_sq (pairwise-8)
#define WS_CF16  4112   // 512*64 f16 centroids (65536 B)
#define WS_LIST  69648  // compact flagged-point list (ws-size-guarded)

__device__ __forceinline__ float csq_pairwise8(const float* row) {
    float r[8];
#pragma unroll
    for (int t = 0; t < 8; ++t) r[t] = __fmul_rn(row[t], row[t]);
#pragma unroll
    for (int b = 1; b < 8; ++b)
#pragma unroll
        for (int t = 0; t < 8; ++t)
            r[t] = __fadd_rn(r[t], __fmul_rn(row[8 * b + t], row[8 * b + t]));
    return __fadd_rn(__fadd_rn(__fadd_rn(r[0], r[1]), __fadd_rn(r[2], r[3])),
                     __fadd_rn(__fadd_rn(r[4], r[5]), __fadd_rn(r[6], r[7])));
}

__global__ __launch_bounds__(256) void prep_kernel(const float* __restrict__ c,
                                                   float* __restrict__ out_c,
                                                   _Float16* __restrict__ cf16,
                                                   float* __restrict__ cs16,
                                                   float* __restrict__ csq) {
    int j = blockIdx.x * 256 + threadIdx.x;
    if (j < KC * DD) {
        float v = c[j];
        out_c[j] = v;
        cf16[j] = (_Float16)v;  // RNE
    }
    if (j < KC) {
        float s = csq_pairwise8(c + j * DD);
        csq[j] = s;
        cs16[j] = s + SHIFT;
    }
}

// R17/R18 approx core (clean: VGPR=40, WRITE 1.2MB, zero conflicts) widened
// to 8 waves/block: same 2 blocks/CU (LDS-capped) but 16 waves/CU = 4/SIMD,
// doubling the TLP that hides the ct-loop's LDS->MFMA->VALU chains (R18:
// Occupancy 20%, VALUBusy 28%, everything <30% loaded = latency-exposed at
// 2 waves/SIMD; unroll-2 proved ILP can't break the b1/b2 dep chains).
// Per-thread state unchanged (lean, 16+16 regs) -- the R7/R8 512-thread
// spills carried 2-4x this state or forced a 64-VGPR cap; no cap here.
__global__ __launch_bounds__(ABLOCK) void approx_kernel(const float* __restrict__ x,
                                                        const _Float16* __restrict__ cf16,
                                                        const float* __restrict__ cs16g,
                                                        float* __restrict__ out_assign,
                                                        int* __restrict__ gcnt,
                                                        int* __restrict__ glist,
                                                        int list_cap) {
    extern __shared__ char smem[];          // [0,64K): swizzled c_f16
    float* scs = (float*)(smem + 65536);    // 512 f32: c_sq + SHIFT
    __shared__ int llist[256];
    __shared__ int lcnt, lbase;

    int tid = threadIdx.x;
    const uint4* src = (const uint4*)cf16;
#pragma unroll
    for (int i = 0; i < 8; ++i) {
        int chunk = tid + i * ABLOCK;       // 4096 chunks of 16B
        int row = chunk >> 3, slot = chunk & 7;
        uint4 v = src[chunk];
        *(uint4*)(smem + row * 128 + ((slot ^ (row & 7)) << 4)) = v;
    }
    scs[tid] = cs16g[tid];

    int wid = tid >> 6, lane = tid & 63;
    int lrow = lane & 15, lgrp = lane >> 4;

    for (int tile = 0; tile < TILES; ++tile) {
        __syncthreads();   // staging done (tile 0) / prior tile compaction done
        if (tid == 0) lcnt = 0;
        int pbase = (blockIdx.x * TILES + tile) * 256 + wid * 32;

        // A-frags (layout proven absmax=0 R4-R18).
        f16x8 a[2][2];
#pragma unroll
        for (int s = 0; s < 2; ++s)
#pragma unroll
            for (int kk = 0; kk < 2; ++kk) {
                const float4* p = (const float4*)(x + (size_t)(pbase + s * 16 + lrow) * DD
                                                  + kk * 32 + lgrp * 8);
                float4 u0 = p[0], u1 = p[1];
                f16x8 t;
                t[0] = (_Float16)u0.x; t[1] = (_Float16)u0.y;
                t[2] = (_Float16)u0.z; t[3] = (_Float16)u0.w;
                t[4] = (_Float16)u1.x; t[5] = (_Float16)u1.y;
                t[6] = (_Float16)u1.z; t[7] = (_Float16)u1.w;
                a[s][kk] = t;
            }

        unsigned b1[2][4], b2[2][4];
#pragma unroll
        for (int s = 0; s < 2; ++s)
#pragma unroll
            for (int r = 0; r < 4; ++r) { b1[s][r] = 0xFFFFFFFFu; b2[s][r] = 0xFFFFFFFFu; }

        int base0 = lrow * 128 + ((lgrp ^ (lane & 7)) << 4);
        int base1 = base0 ^ 64;
        int centv = lrow;

        for (int ct = 0; ct < 32; ++ct) {
            f16x8 bk0 = *(const f16x8*)(smem + base0);
            f16x8 bk1 = *(const f16x8*)(smem + base1);
            float cs = scs[centv];
            f32x4 acc0 = {0.f, 0.f, 0.f, 0.f}, acc1 = {0.f, 0.f, 0.f, 0.f};
            acc0 = __builtin_amdgcn_mfma_f32_16x16x32_f16(a[0][0], bk0, acc0, 0, 0, 0);
            acc0 = __builtin_amdgcn_mfma_f32_16x16x32_f16(a[0][1], bk1, acc0, 0, 0, 0);
            acc1 = __builtin_amdgcn_mfma_f32_16x16x32_f16(a[1][0], bk0, acc1, 0, 0, 0);
            acc1 = __builtin_amdgcn_mfma_f32_16x16x32_f16(a[1][1], bk1, acc1, 0, 0, 0);
#pragma unroll
            for (int r = 0; r < 4; ++r) {
                float d0 = __builtin_fmaf(-2.0f, acc0[r], cs);
                float d1 = __builtin_fmaf(-2.0f, acc1[r], cs);
                unsigned k0 = (__float_as_uint(d0) & 0xFFFFFE00u) | (unsigned)centv;
                unsigned k1 = (__float_as_uint(d1) & 0xFFFFFE00u) | (unsigned)centv;
                unsigned m0 = max(b1[0][r], k0);
                b1[0][r] = min(b1[0][r], k0);
                b2[0][r] = min(b2[0][r], m0);
                unsigned m1 = max(b1[1][r], k1);
                b1[1][r] = min(b1[1][r], k1);
                b2[1][r] = min(b2[1][r], m1);
            }
            base0 += 2048; base1 += 2048; centv += 16;
        }

#pragma unroll
        for (int d = 1; d < 16; d <<= 1) {
#pragma unroll
            for (int s = 0; s < 2; ++s)
#pragma unroll
                for (int r = 0; r < 4; ++r) {
                    unsigned o1 = (unsigned)__shfl_xor((int)b1[s][r], d);
                    unsigned o2 = (unsigned)__shfl_xor((int)b2[s][r], d);
                    unsigned mx = max(b1[s][r], o1);
                    b1[s][r] = min(b1[s][r], o1);
                    b2[s][r] = min(min(b2[s][r], o2), mx);
                }
        }

        __syncthreads();   // lcnt reset visible before flag atomics
        if (lrow == 0) {
#pragma unroll
            for (int s = 0; s < 2; ++s)
#pragma unroll
                for (int r = 0; r < 4; ++r) {
                    int p = pbase + s * 16 + lgrp * 4 + r;
                    unsigned w = b1[s][r];
                    float d1 = __uint_as_float(w & 0xFFFFFE00u);
                    float d2 = __uint_as_float(b2[s][r] & 0xFFFFFE00u);
                    out_assign[p] = (float)(w & 0x1FFu);
                    if (d2 - d1 <= MARGIN) {
                        int t = atomicAdd(&lcnt, 1);
                        llist[t] = p;      // max 256 == points/tile: no overflow
                    }
                }
        }
        __syncthreads();   // flags complete
        int n = lcnt;
        if (tid == 0) lbase = n ? atomicAdd(gcnt, n) : 0;
        __syncthreads();   // lbase visible
        for (int t = tid; t < n; t += ABLOCK) {
            int idx = lbase + t;
            if (idx < list_cap) glist[idx] = llist[t];
            else {
                out_assign[llist[t]] = SENTINEL;   // ws too small: fallback fixes
                atomicAdd(gcnt + 1, 1);            // overflow count (rare)
            }
        }
    }
}

// Rescore (R16-R18 proven, byte-identical): wave per 2 points, lane-split k
// from LDS-staged f32 centroids, wave-uniform x -> s_loads.
__global__ __launch_bounds__(256) void rescore_kernel(const float* __restrict__ x,
                                                      const float* __restrict__ c,
                                                      const float* __restrict__ csq,
                                                      const int* __restrict__ gcnt,
                                                      const int* __restrict__ glist,
                                                      int list_cap,
                                                      float* __restrict__ out_assign) {
    extern __shared__ char rsm[];
    float* cs = (float*)rsm;                       // [512][68] f32
    float* scsq = (float*)(rsm + KC * CSTRIDE * 4);// 512 f32

    int tid = threadIdx.x;
    int n = *gcnt;
    if (n > list_cap) n = list_cap;
    scsq[tid] = csq[tid];
    scsq[tid + 256] = csq[tid + 256];
#pragma unroll
    for (int it = 0; it < 32; ++it) {
        int idx = tid + it * 256;                  // 8192 float4 chunks
        int row = idx >> 4, q = idx & 15;
        float4 v = ((const float4*)(c + row * DD))[q];
        float* d = &cs[row * CSTRIDE + q * 4];
        d[0] = v.x; d[1] = v.y; d[2] = v.z; d[3] = v.w;
    }
    __syncthreads();
    if (n <= 0) return;

    int wid = tid >> 6, lane = tid & 63;
    int gw = blockIdx.x * 4 + wid;
    int stride2 = 256 * 4 * 2;

    for (int t0 = gw * 2; t0 < n; t0 += stride2) {
        int iA = __builtin_amdgcn_readfirstlane(glist[t0]);
        int t1 = (t0 + 1 < n) ? t0 + 1 : t0;
        int iB = __builtin_amdgcn_readfirstlane(glist[t1]);
        const float* xA = x + (size_t)iA * DD;     // wave-uniform -> s_loads
        const float* xB = x + (size_t)iB * DD;
        float xsqA = csq_pairwise8(xA);
        float xsqB = csq_pairwise8(xB);

        unsigned long long bA = ~0ull, bB = ~0ull;
#pragma unroll 1
        for (int j = 0; j < 8; ++j) {
            int k = j * 64 + lane;
            const float* crow = &cs[k * CSTRIDE];
            float a0 = 0.f, a1 = 0.f, a2 = 0.f, a3 = 0.f;
            float c0 = 0.f, c1 = 0.f, c2 = 0.f, c3 = 0.f;
#pragma unroll
            for (int q = 0; q < 16; ++q) {
                float4 cq = *(const float4*)(crow + q * 4);   // LDS b128
                a0 = __fmaf_rn(xA[4 * q + 0], cq.x, a0);
                a1 = __fmaf_rn(xA[4 * q + 1], cq.y, a1);
                a2 = __fmaf_rn(xA[4 * q + 2], cq.z, a2);
                a3 = __fmaf_rn(xA[4 * q + 3], cq.w, a3);
                c0 = __fmaf_rn(xB[4 * q + 0], cq.x, c0);
                c1 = __fmaf_rn(xB[4 * q + 1], cq.y, c1);
                c2 = __fmaf_rn(xB[4 * q + 2], cq.z, c2);
                c3 = __fmaf_rn(xB[4 * q + 3], cq.w, c3);
            }
            float sq = scsq[k];
            float accA = __fadd_rn(__fadd_rn(a0, a1), __fadd_rn(a2, a3));
            float accB = __fadd_rn(__fadd_rn(c0, c1), __fadd_rn(c2, c3));
            float dA = __fmaf_rn(-2.0f, accA, __fadd_rn(xsqA, sq));
            float dB = __fmaf_rn(-2.0f, accB, __fadd_rn(xsqB, sq));
            unsigned long long kA =
                ((unsigned long long)__float_as_uint(dA) << 32) | (unsigned)k;
            unsigned long long kB =
                ((unsigned long long)__float_as_uint(dB) << 32) | (unsigned)k;
            bA = bA < kA ? bA : kA;
            bB = bB < kB ? bB : kB;
        }
#pragma unroll
        for (int dd = 1; dd < 64; dd <<= 1) {
            unsigned hiA = (unsigned)__shfl_xor((int)(bA >> 32), dd);
            unsigned loA = (unsigned)__shfl_xor((int)(bA & 0xFFFFFFFFull), dd);
            unsigned long long oA = ((unsigned long long)hiA << 32) | loA;
            bA = bA < oA ? bA : oA;
            unsigned hiB = (unsigned)__shfl_xor((int)(bB >> 32), dd);
            unsigned loB = (unsigned)__shfl_xor((int)(bB & 0xFFFFFFFFull), dd);
            unsigned long long oB = ((unsigned long long)hiB << 32) | loB;
            bB = bB < oB ? bB : oB;
        }
        if (lane == 0) {
            out_assign[iA] = (float)(unsigned)(bA & 0xFFFFFFFFull);
            out_assign[iB] = (float)(unsigned)(bB & 0xFFFFFFFFull);
        }
    }
}

// Fallback: only runs if the compact list overflowed (gcnt[1] > 0 -- normally
// zero, so every block exits after one cached scalar read).
__global__ __launch_bounds__(256) void fallback_kernel(const float* __restrict__ x,
                                                       const float* __restrict__ c,
                                                       const float* __restrict__ csq,
                                                       const int* __restrict__ gcnt,
                                                       float* __restrict__ out_assign) {
    if (gcnt[1] == 0) return;               // no overflow: launch-overhead only
    int p = blockIdx.x * 256 + threadIdx.x;
    int lane = threadIdx.x & 63;
    float v = out_assign[p];
    unsigned long long mask = __ballot(v < 0.0f);
    int wbase = p & ~63;

    while (mask) {
        int b = __ffsll((long long)mask) - 1;
        mask &= mask - 1;
        int i = wbase + b;
        const float* xr = x + (size_t)i * DD;

        float x_sq = csq_pairwise8(xr);
        unsigned long long best = ~0ull;
#pragma unroll 1
        for (int j = 0; j < 8; ++j) {
            int k = j * 64 + lane;
            const float* crow = c + (size_t)k * DD;
            float a0 = 0.f, a1 = 0.f, a2 = 0.f, a3 = 0.f;
#pragma unroll
            for (int d = 0; d < DD; d += 4) {
                a0 = __fmaf_rn(xr[d + 0], crow[d + 0], a0);
                a1 = __fmaf_rn(xr[d + 1], crow[d + 1], a1);
                a2 = __fmaf_rn(xr[d + 2], crow[d + 2], a2);
                a3 = __fmaf_rn(xr[d + 3], crow[d + 3], a3);
            }
            float acc = __fadd_rn(__fadd_rn(a0, a1), __fadd_rn(a2, a3));
            float tt = __fadd_rn(x_sq, csq[k]);
            float dist = __fmaf_rn(-2.0f, acc, tt);
            unsigned long long key =
                ((unsigned long long)__float_as_uint(dist) << 32) | (unsigned)k;
            best = best < key ? best : key;
        }
#pragma unroll
        for (int dd = 1; dd < 64; dd <<= 1) {
            unsigned hi = (unsigned)__shfl_xor((int)(best >> 32), dd);
            unsigned lo = (unsigned)__shfl_xor((int)(best & 0xFFFFFFFFull), dd);
            unsigned long long o = ((unsigned long long)hi << 32) | lo;
            best = best < o ? best : o;
        }
        if (lane == 0) out_assign[i] = (float)(unsigned)(best & 0xFFFFFFFFull);
    }
}

extern "C" void kernel_launch(void* const* d_in, const int* in_sizes, int n_in,
                              void* d_out, int out_size, void* d_ws, size_t ws_size,
                              hipStream_t stream) {
    const float* x = (const float*)d_in[0];
    const float* c = (const float*)d_in[1];
    float* out = (float*)d_out;
    float* out_assign = out + KC * DD;

    char* ws = (char*)d_ws;
    int* gcnt = (int*)(ws + WS_GCNT);
    float* cs16 = (float*)(ws + WS_CS16);
    float* csq = (float*)(ws + WS_CSQ);
    _Float16* cf16 = (_Float16*)(ws + WS_CF16);
    int* glist = (int*)(ws + WS_LIST);
    int list_cap = 0;
    if (ws_size > WS_LIST + 4) {
        size_t cap = (ws_size - WS_LIST) / 4;
        list_cap = cap > NPTS ? NPTS : (int)cap;
    }

    hipMemsetAsync(gcnt, 0, 16, stream);
    prep_kernel<<<(KC * DD + 255) / 256, 256, 0, stream>>>(c, out, cf16, cs16, csq);
    approx_kernel<<<NPTS / (256 * TILES), ABLOCK, 67584, stream>>>(
        x, cf16, cs16, out_assign, gcnt, glist, list_cap);
    rescore_kernel<<<256, 256, KC * CSTRIDE * 4 + 2048, stream>>>(
        x, c, csq, gcnt, glist, list_cap, out_assign);
    fallback_kernel<<<NPTS / 256, 256, 0, stream>>>(x, c, csq, gcnt, out_assign);
}

// Round 20
// 154.225 us; speedup vs baseline: 3.0807x; 1.0104x over previous
//
#include <hip/hip_runtime.h>
#include <math.h>

#define NPTS 262144
#define KC 512
#define DD 64
#define MARGIN 0.02f
#define SHIFT 32.0f
#define SENTINEL -1.0f
#define CSTRIDE 68            // f32 row stride in LDS for rescore
#define ABLOCK 512            // approx block: 8 waves
#define TILES 2               // 256-point tiles per approx block

typedef _Float16 f16x8 __attribute__((ext_vector_type(8)));
typedef float f32x4 __attribute__((ext_vector_type(4)));

// ws layout (bytes)
#define WS_GCNT  0      // int[4]: [0] list counter, [1] overflow count (memset)
#define WS_CS16  16     // 512 f32: c_sq + SHIFT
#define WS_CSQ   2064   // 512 f32: exact c_sq (pairwise-8)
#define WS_CF16  4112   // 512*64 f16 centroids (65536 B)
#define WS_LIST  69648  // compact flagged-point list (ws-size-guarded)

__device__ __forceinline__ float csq_pairwise8(const float* row) {
    float r[8];
#pragma unroll
    for (int t = 0; t < 8; ++t) r[t] = __fmul_rn(row[t], row[t]);
#pragma unroll
    for (int b = 1; b < 8; ++b)
#pragma unroll
        for (int t = 0; t < 8; ++t)
            r[t] = __fadd_rn(r[t], __fmul_rn(row[8 * b + t], row[8 * b + t]));
    return __fadd_rn(__fadd_rn(__fadd_rn(r[0], r[1]), __fadd_rn(r[2], r[3])),
                     __fadd_rn(__fadd_rn(r[4], r[5]), __fadd_rn(r[6], r[7])));
}

__global__ __launch_bounds__(256) void prep_kernel(const float* __restrict__ c,
                                                   float* __restrict__ out_c,
                                                   _Float16* __restrict__ cf16,
                                                   float* __restrict__ cs16,
                                                   float* __restrict__ csq) {
    int j = blockIdx.x * 256 + threadIdx.x;
    if (j < KC * DD) {
        float v = c[j];
        out_c[j] = v;
        cf16[j] = (_Float16)v;  // RNE
    }
    if (j < KC) {
        float s = csq_pairwise8(c + j * DD);
        csq[j] = s;
        cs16[j] = s + SHIFT;
    }
}

// R19 approx shape (8 waves, 2 tiles, clean VGPR=40/WRITE 1.2MB) with the
// ct-loop's serial chain broken at source:
//  1) register double-buffer: iter+1's B-frags loaded BEFORE the epilogue
//     (compiler wasn't hoisting; lgkm drain serialized each iter). Final
//     prefetch reads smem[67568..67584) -- in-bounds, never consumed.
//  2) split accumulators: 4 INDEPENDENT zero-init MFMAs (chained C-in pairs
//     serialized ~100cy/iter); combined with one fadd per distance (adds
//     ~1e-6 rounding to an approx distance with 0.019 < MARGIN error budget).
__global__ __launch_bounds__(ABLOCK) void approx_kernel(const float* __restrict__ x,
                                                        const _Float16* __restrict__ cf16,
                                                        const float* __restrict__ cs16g,
                                                        float* __restrict__ out_assign,
                                                        int* __restrict__ gcnt,
                                                        int* __restrict__ glist,
                                                        int list_cap) {
    extern __shared__ char smem[];          // [0,64K): swizzled c_f16 | [64K,66K): scs
    float* scs = (float*)(smem + 65536);    // 512 f32: c_sq + SHIFT
    __shared__ int llist[256];
    __shared__ int lcnt, lbase;

    int tid = threadIdx.x;
    const uint4* src = (const uint4*)cf16;
#pragma unroll
    for (int i = 0; i < 8; ++i) {
        int chunk = tid + i * ABLOCK;       // 4096 chunks of 16B
        int row = chunk >> 3, slot = chunk & 7;
        uint4 v = src[chunk];
        *(uint4*)(smem + row * 128 + ((slot ^ (row & 7)) << 4)) = v;
    }
    scs[tid] = cs16g[tid];

    int wid = tid >> 6, lane = tid & 63;
    int lrow = lane & 15, lgrp = lane >> 4;

    for (int tile = 0; tile < TILES; ++tile) {
        __syncthreads();   // staging done (tile 0) / prior tile compaction done
        if (tid == 0) lcnt = 0;
        int pbase = (blockIdx.x * TILES + tile) * 256 + wid * 32;

        // A-frags (layout proven absmax=0 R4-R19).
        f16x8 a[2][2];
#pragma unroll
        for (int s = 0; s < 2; ++s)
#pragma unroll
            for (int kk = 0; kk < 2; ++kk) {
                const float4* p = (const float4*)(x + (size_t)(pbase + s * 16 + lrow) * DD
                                                  + kk * 32 + lgrp * 8);
                float4 u0 = p[0], u1 = p[1];
                f16x8 t;
                t[0] = (_Float16)u0.x; t[1] = (_Float16)u0.y;
                t[2] = (_Float16)u0.z; t[3] = (_Float16)u0.w;
                t[4] = (_Float16)u1.x; t[5] = (_Float16)u1.y;
                t[6] = (_Float16)u1.z; t[7] = (_Float16)u1.w;
                a[s][kk] = t;
            }

        unsigned b1[2][4], b2[2][4];
#pragma unroll
        for (int s = 0; s < 2; ++s)
#pragma unroll
            for (int r = 0; r < 4; ++r) { b1[s][r] = 0xFFFFFFFFu; b2[s][r] = 0xFFFFFFFFu; }

        int base0 = lrow * 128 + ((lgrp ^ (lane & 7)) << 4);
        int base1 = base0 ^ 64;
        int centv = lrow;

        // Register double-buffer: nb holds iter's B-frags, prefetched early.
        f16x8 nb0 = *(const f16x8*)(smem + base0);
        f16x8 nb1 = *(const f16x8*)(smem + base1);

        for (int ct = 0; ct < 32; ++ct) {
            f16x8 bk0 = nb0, bk1 = nb1;
            base0 += 2048; base1 += 2048;
            nb0 = *(const f16x8*)(smem + base0);   // prefetch iter+1 (final
            nb1 = *(const f16x8*)(smem + base1);   //  read in-bounds, unused)
            float cs = scs[centv];
            int kv = centv;
            centv += 16;

            // 4 independent MFMAs (no C-in chaining).
            f32x4 z = {0.f, 0.f, 0.f, 0.f};
            f32x4 p0a = __builtin_amdgcn_mfma_f32_16x16x32_f16(a[0][0], bk0, z, 0, 0, 0);
            f32x4 p0b = __builtin_amdgcn_mfma_f32_16x16x32_f16(a[0][1], bk1, z, 0, 0, 0);
            f32x4 p1a = __builtin_amdgcn_mfma_f32_16x16x32_f16(a[1][0], bk0, z, 0, 0, 0);
            f32x4 p1b = __builtin_amdgcn_mfma_f32_16x16x32_f16(a[1][1], bk1, z, 0, 0, 0);
#pragma unroll
            for (int r = 0; r < 4; ++r) {
                float d0 = __builtin_fmaf(-2.0f, __fadd_rn(p0a[r], p0b[r]), cs);
                float d1 = __builtin_fmaf(-2.0f, __fadd_rn(p1a[r], p1b[r]), cs);
                unsigned k0 = (__float_as_uint(d0) & 0xFFFFFE00u) | (unsigned)kv;
                unsigned k1 = (__float_as_uint(d1) & 0xFFFFFE00u) | (unsigned)kv;
                unsigned m0 = max(b1[0][r], k0);
                b1[0][r] = min(b1[0][r], k0);
                b2[0][r] = min(b2[0][r], m0);
                unsigned m1 = max(b1[1][r], k1);
                b1[1][r] = min(b1[1][r], k1);
                b2[1][r] = min(b2[1][r], m1);
            }
        }

#pragma unroll
        for (int d = 1; d < 16; d <<= 1) {
#pragma unroll
            for (int s = 0; s < 2; ++s)
#pragma unroll
                for (int r = 0; r < 4; ++r) {
                    unsigned o1 = (unsigned)__shfl_xor((int)b1[s][r], d);
                    unsigned o2 = (unsigned)__shfl_xor((int)b2[s][r], d);
                    unsigned mx = max(b1[s][r], o1);
                    b1[s][r] = min(b1[s][r], o1);
                    b2[s][r] = min(min(b2[s][r], o2), mx);
                }
        }

        __syncthreads();   // lcnt reset visible before flag atomics
        if (lrow == 0) {
#pragma unroll
            for (int s = 0; s < 2; ++s)
#pragma unroll
                for (int r = 0; r < 4; ++r) {
                    int p = pbase + s * 16 + lgrp * 4 + r;
                    unsigned w = b1[s][r];
                    float d1 = __uint_as_float(w & 0xFFFFFE00u);
                    float d2 = __uint_as_float(b2[s][r] & 0xFFFFFE00u);
                    out_assign[p] = (float)(w & 0x1FFu);
                    if (d2 - d1 <= MARGIN) {
                        int t = atomicAdd(&lcnt, 1);
                        llist[t] = p;      // max 256 == points/tile: no overflow
                    }
                }
        }
        __syncthreads();   // flags complete
        int n = lcnt;
        if (tid == 0) lbase = n ? atomicAdd(gcnt, n) : 0;
        __syncthreads();   // lbase visible
        for (int t = tid; t < n; t += ABLOCK) {
            int idx = lbase + t;
            if (idx < list_cap) glist[idx] = llist[t];
            else {
                out_assign[llist[t]] = SENTINEL;   // ws too small: fallback fixes
                atomicAdd(gcnt + 1, 1);            // overflow count (rare)
            }
        }
    }
}

// Rescore (R16-R19 proven, byte-identical): wave per 2 points, lane-split k
// from LDS-staged f32 centroids, wave-uniform x -> s_loads.
__global__ __launch_bounds__(256) void rescore_kernel(const float* __restrict__ x,
                                                      const float* __restrict__ c,
                                                      const float* __restrict__ csq,
                                                      const int* __restrict__ gcnt,
                                                      const int* __restrict__ glist,
                                                      int list_cap,
                                                      float* __restrict__ out_assign) {
    extern __shared__ char rsm[];
    float* cs = (float*)rsm;                       // [512][68] f32
    float* scsq = (float*)(rsm + KC * CSTRIDE * 4);// 512 f32

    int tid = threadIdx.x;
    int n = *gcnt;
    if (n > list_cap) n = list_cap;
    scsq[tid] = csq[tid];
    scsq[tid + 256] = csq[tid + 256];
#pragma unroll
    for (int it = 0; it < 32; ++it) {
        int idx = tid + it * 256;                  // 8192 float4 chunks
        int row = idx >> 4, q = idx & 15;
        float4 v = ((const float4*)(c + row * DD))[q];
        float* d = &cs[row * CSTRIDE + q * 4];
        d[0] = v.x; d[1] = v.y; d[2] = v.z; d[3] = v.w;
    }
    __syncthreads();
    if (n <= 0) return;

    int wid = tid >> 6, lane = tid & 63;
    int gw = blockIdx.x * 4 + wid;
    int stride2 = 256 * 4 * 2;

    for (int t0 = gw * 2; t0 < n; t0 += stride2) {
        int iA = __builtin_amdgcn_readfirstlane(glist[t0]);
        int t1 = (t0 + 1 < n) ? t0 + 1 : t0;
        int iB = __builtin_amdgcn_readfirstlane(glist[t1]);
        const float* xA = x + (size_t)iA * DD;     // wave-uniform -> s_loads
        const float* xB = x + (size_t)iB * DD;
        float xsqA = csq_pairwise8(xA);
        float xsqB = csq_pairwise8(xB);

        unsigned long long bA = ~0ull, bB = ~0ull;
#pragma unroll 1
        for (int j = 0; j < 8; ++j) {
            int k = j * 64 + lane;
            const float* crow = &cs[k * CSTRIDE];
            float a0 = 0.f, a1 = 0.f, a2 = 0.f, a3 = 0.f;
            float c0 = 0.f, c1 = 0.f, c2 = 0.f, c3 = 0.f;
#pragma unroll
            for (int q = 0; q < 16; ++q) {
                float4 cq = *(const float4*)(crow + q * 4);   // LDS b128
                a0 = __fmaf_rn(xA[4 * q + 0], cq.x, a0);
                a1 = __fmaf_rn(xA[4 * q + 1], cq.y, a1);
                a2 = __fmaf_rn(xA[4 * q + 2], cq.z, a2);
                a3 = __fmaf_rn(xA[4 * q + 3], cq.w, a3);
                c0 = __fmaf_rn(xB[4 * q + 0], cq.x, c0);
                c1 = __fmaf_rn(xB[4 * q + 1], cq.y, c1);
                c2 = __fmaf_rn(xB[4 * q + 2], cq.z, c2);
                c3 = __fmaf_rn(xB[4 * q + 3], cq.w, c3);
            }
            float sq = scsq[k];
            float accA = __fadd_rn(__fadd_rn(a0, a1), __fadd_rn(a2, a3));
            float accB = __fadd_rn(__fadd_rn(c0, c1), __fadd_rn(c2, c3));
            float dA = __fmaf_rn(-2.0f, accA, __fadd_rn(xsqA, sq));
            float dB = __fmaf_rn(-2.0f, accB, __fadd_rn(xsqB, sq));
            unsigned long long kA =
                ((unsigned long long)__float_as_uint(dA) << 32) | (unsigned)k;
            unsigned long long kB =
                ((unsigned long long)__float_as_uint(dB) << 32) | (unsigned)k;
            bA = bA < kA ? bA : kA;
            bB = bB < kB ? bB : kB;
        }
#pragma unroll
        for (int dd = 1; dd < 64; dd <<= 1) {
            unsigned hiA = (unsigned)__shfl_xor((int)(bA >> 32), dd);
            unsigned loA = (unsigned)__shfl_xor((int)(bA & 0xFFFFFFFFull), dd);
            unsigned long long oA = ((unsigned long long)hiA << 32) | loA;
            bA = bA < oA ? bA : oA;
            unsigned hiB = (unsigned)__shfl_xor((int)(bB >> 32), dd);
            unsigned loB = (unsigned)__shfl_xor((int)(bB & 0xFFFFFFFFull), dd);
            unsigned long long oB = ((unsigned long long)hiB << 32) | loB;
            bB = bB < oB ? bB : oB;
        }
        if (lane == 0) {
            out_assign[iA] = (float)(unsigned)(bA & 0xFFFFFFFFull);
            out_assign[iB] = (float)(unsigned)(bB & 0xFFFFFFFFull);
        }
    }
}

// Fallback: only runs if the compact list overflowed (gcnt[1] > 0 -- normally
// zero, so every block exits after one cached scalar read).
__global__ __launch_bounds__(256) void fallback_kernel(const float* __restrict__ x,
                                                       const float* __restrict__ c,
                                                       const float* __restrict__ csq,
                                                       const int* __restrict__ gcnt,
                                                       float* __restrict__ out_assign) {
    if (gcnt[1] == 0) return;               // no overflow: launch-overhead only
    int p = blockIdx.x * 256 + threadIdx.x;
    int lane = threadIdx.x & 63;
    float v = out_assign[p];
    unsigned long long mask = __ballot(v < 0.0f);
    int wbase = p & ~63;

    while (mask) {
        int b = __ffsll((long long)mask) - 1;
        mask &= mask - 1;
        int i = wbase + b;
        const float* xr = x + (size_t)i * DD;

        float x_sq = csq_pairwise8(xr);
        unsigned long long best = ~0ull;
#pragma unroll 1
        for (int j = 0; j < 8; ++j) {
            int k = j * 64 + lane;
            const float* crow = c + (size_t)k * DD;
            float a0 = 0.f, a1 = 0.f, a2 = 0.f, a3 = 0.f;
#pragma unroll
            for (int d = 0; d < DD; d += 4) {
                a0 = __fmaf_rn(xr[d + 0], crow[d + 0], a0);
                a1 = __fmaf_rn(xr[d + 1], crow[d + 1], a1);
                a2 = __fmaf_rn(xr[d + 2], crow[d + 2], a2);
                a3 = __fmaf_rn(xr[d + 3], crow[d + 3], a3);
            }
            float acc = __fadd_rn(__fadd_rn(a0, a1), __fadd_rn(a2, a3));
            float tt = __fadd_rn(x_sq, csq[k]);
            float dist = __fmaf_rn(-2.0f, acc, tt);
            unsigned long long key =
                ((unsigned long long)__float_as_uint(dist) << 32) | (unsigned)k;
            best = best < key ? best : key;
        }
#pragma unroll
        for (int dd = 1; dd < 64; dd <<= 1) {
            unsigned hi = (unsigned)__shfl_xor((int)(best >> 32), dd);
            unsigned lo = (unsigned)__shfl_xor((int)(best & 0xFFFFFFFFull), dd);
            unsigned long long o = ((unsigned long long)hi << 32) | lo;
            best = best < o ? best : o;
        }
        if (lane == 0) out_assign[i] = (float)(unsigned)(best & 0xFFFFFFFFull);
    }
}

extern "C" void kernel_launch(void* const* d_in, const int* in_sizes, int n_in,
                              void* d_out, int out_size, void* d_ws, size_t ws_size,
                              hipStream_t stream) {
    const float* x = (const float*)d_in[0];
    const float* c = (const float*)d_in[1];
    float* out = (float*)d_out;
    float* out_assign = out + KC * DD;

    char* ws = (char*)d_ws;
    int* gcnt = (int*)(ws + WS_GCNT);
    float* cs16 = (float*)(ws + WS_CS16);
    float* csq = (float*)(ws + WS_CSQ);
    _Float16* cf16 = (_Float16*)(ws + WS_CF16);
    int* glist = (int*)(ws + WS_LIST);
    int list_cap = 0;
    if (ws_size > WS_LIST + 4) {
        size_t cap = (ws_size - WS_LIST) / 4;
        list_cap = cap > NPTS ? NPTS : (int)cap;
    }

    hipMemsetAsync(gcnt, 0, 16, stream);
    prep_kernel<<<(KC * DD + 255) / 256, 256, 0, stream>>>(c, out, cf16, cs16, csq);
    approx_kernel<<<NPTS / (256 * TILES), ABLOCK, 67584, stream>>>(
        x, cf16, cs16, out_assign, gcnt, glist, list_cap);
    rescore_kernel<<<256, 256, KC * CSTRIDE * 4 + 2048, stream>>>(
        x, c, csq, gcnt, glist, list_cap, out_assign);
    fallback_kernel<<<NPTS / 256, 256, 0, stream>>>(x, c, csq, gcnt, out_assign);
}

// Round 22
// 124.499 us; speedup vs baseline: 3.8163x; 1.2388x over previous
//
#include <hip/hip_runtime.h>
#include <math.h>

#define NPTS 262144
#define KC 512
#define DD 64
#define MARGIN 0.02f
#define SHIFT 32.0f
#define SENTINEL -1.0f
#define CSTRIDE 68            // f32 row stride in LDS for rescore
#define ABLOCK 512            // approx block: 8 waves
#define TILES 2               // 256-point tiles per approx block

typedef _Float16 f16x8 __attribute__((ext_vector_type(8)));
typedef _Float16 f16x4 __attribute__((ext_vector_type(4)));
typedef float f32x4 __attribute__((ext_vector_type(4)));

__device__ __forceinline__ float csq_pairwise8(const float* row) {
    float r[8];
#pragma unroll
    for (int t = 0; t < 8; ++t) r[t] = __fmul_rn(row[t], row[t]);
#pragma unroll
    for (int b = 1; b < 8; ++b)
#pragma unroll
        for (int t = 0; t < 8; ++t)
            r[t] = __fadd_rn(r[t], __fmul_rn(row[8 * b + t], row[8 * b + t]));
    return __fadd_rn(__fadd_rn(__fadd_rn(r[0], r[1]), __fadd_rn(r[2], r[3])),
                     __fadd_rn(__fadd_rn(r[4], r[5]), __fadd_rn(r[6], r[7])));
}

// Self-prepping approx (R21 structure, staging-count bug fixed: f32 source is
// 8192 chunks -> 16 iterations, not 8 -- R21 left rows 256-511 unstaged).
// Stages f16 from f32 c, computes approx csq+SHIFT during staging (16-lane
// shfl tree, single writer/row, ~1e-5 err inside margin slack). Flagged
// points get SENTINEL; pure function, no atomics/lists/ws. ct-loop = R20.
__global__ __launch_bounds__(ABLOCK) void approx_kernel(const float* __restrict__ x,
                                                        const float* __restrict__ c,
                                                        float* __restrict__ out_assign) {
    extern __shared__ char smem[];          // [0,64K): swizzled c_f16 | [64K,66K): scs
    float* scs = (float*)(smem + 65536);    // 512 f32: csq_approx + SHIFT

    int tid = threadIdx.x;
    const float4* src = (const float4*)c;
#pragma unroll
    for (int i = 0; i < 16; ++i) {          // 16 x 512 = 8192 f32x4 chunks = 512 rows
        int chunk = tid + i * ABLOCK;
        int row = chunk >> 4, q = chunk & 15;
        float4 v = src[chunk];
        f16x4 h;
        h[0] = (_Float16)v.x; h[1] = (_Float16)v.y;
        h[2] = (_Float16)v.z; h[3] = (_Float16)v.w;
        int off = row * 128 + (((q >> 1) ^ (row & 7)) << 4) + (q & 1) * 8;
        *(f16x4*)(smem + off) = h;
        // Row csq: 16 chunks of a row sit on an aligned 16-lane group
        // (512 % 16 == 0), xor-tree reduce; q==0 lane writes.
        float s = (v.x * v.x + v.y * v.y) + (v.z * v.z + v.w * v.w);
#pragma unroll
        for (int m = 1; m < 16; m <<= 1) s += __shfl_xor(s, m);
        if (q == 0) scs[row] = s + SHIFT;
    }

    int wid = tid >> 6, lane = tid & 63;
    int lrow = lane & 15, lgrp = lane >> 4;

    for (int tile = 0; tile < TILES; ++tile) {
        __syncthreads();   // staging/scs done (tile 0); smem stable afterwards
        int pbase = (blockIdx.x * TILES + tile) * 256 + wid * 32;

        // A-frags (layout proven absmax=0 R4-R20).
        f16x8 a[2][2];
#pragma unroll
        for (int s = 0; s < 2; ++s)
#pragma unroll
            for (int kk = 0; kk < 2; ++kk) {
                const float4* p = (const float4*)(x + (size_t)(pbase + s * 16 + lrow) * DD
                                                  + kk * 32 + lgrp * 8);
                float4 u0 = p[0], u1 = p[1];
                f16x8 t;
                t[0] = (_Float16)u0.x; t[1] = (_Float16)u0.y;
                t[2] = (_Float16)u0.z; t[3] = (_Float16)u0.w;
                t[4] = (_Float16)u1.x; t[5] = (_Float16)u1.y;
                t[6] = (_Float16)u1.z; t[7] = (_Float16)u1.w;
                a[s][kk] = t;
            }

        unsigned b1[2][4], b2[2][4];
#pragma unroll
        for (int s = 0; s < 2; ++s)
#pragma unroll
            for (int r = 0; r < 4; ++r) { b1[s][r] = 0xFFFFFFFFu; b2[s][r] = 0xFFFFFFFFu; }

        int base0 = lrow * 128 + ((lgrp ^ (lane & 7)) << 4);
        int base1 = base0 ^ 64;
        int centv = lrow;

        // Register double-buffer (R20); final prefetch lands in scs region
        // (smem[..67584)) -- in-bounds, never consumed.
        f16x8 nb0 = *(const f16x8*)(smem + base0);
        f16x8 nb1 = *(const f16x8*)(smem + base1);

        for (int ct = 0; ct < 32; ++ct) {
            f16x8 bk0 = nb0, bk1 = nb1;
            base0 += 2048; base1 += 2048;
            nb0 = *(const f16x8*)(smem + base0);
            nb1 = *(const f16x8*)(smem + base1);
            float cs = scs[centv];
            int kv = centv;
            centv += 16;

            f32x4 z = {0.f, 0.f, 0.f, 0.f};
            f32x4 p0a = __builtin_amdgcn_mfma_f32_16x16x32_f16(a[0][0], bk0, z, 0, 0, 0);
            f32x4 p0b = __builtin_amdgcn_mfma_f32_16x16x32_f16(a[0][1], bk1, z, 0, 0, 0);
            f32x4 p1a = __builtin_amdgcn_mfma_f32_16x16x32_f16(a[1][0], bk0, z, 0, 0, 0);
            f32x4 p1b = __builtin_amdgcn_mfma_f32_16x16x32_f16(a[1][1], bk1, z, 0, 0, 0);
#pragma unroll
            for (int r = 0; r < 4; ++r) {
                float d0 = __builtin_fmaf(-2.0f, __fadd_rn(p0a[r], p0b[r]), cs);
                float d1 = __builtin_fmaf(-2.0f, __fadd_rn(p1a[r], p1b[r]), cs);
                unsigned k0 = (__float_as_uint(d0) & 0xFFFFFE00u) | (unsigned)kv;
                unsigned k1 = (__float_as_uint(d1) & 0xFFFFFE00u) | (unsigned)kv;
                unsigned m0 = max(b1[0][r], k0);
                b1[0][r] = min(b1[0][r], k0);
                b2[0][r] = min(b2[0][r], m0);
                unsigned m1 = max(b1[1][r], k1);
                b1[1][r] = min(b1[1][r], k1);
                b2[1][r] = min(b2[1][r], m1);
            }
        }

#pragma unroll
        for (int d = 1; d < 16; d <<= 1) {
#pragma unroll
            for (int s = 0; s < 2; ++s)
#pragma unroll
                for (int r = 0; r < 4; ++r) {
                    unsigned o1 = (unsigned)__shfl_xor((int)b1[s][r], d);
                    unsigned o2 = (unsigned)__shfl_xor((int)b2[s][r], d);
                    unsigned mx = max(b1[s][r], o1);
                    b1[s][r] = min(b1[s][r], o1);
                    b2[s][r] = min(min(b2[s][r], o2), mx);
                }
        }

        // Branchless write: ambiguous -> SENTINEL (rescore repairs), else k.
        if (lrow == 0) {
#pragma unroll
            for (int s = 0; s < 2; ++s)
#pragma unroll
                for (int r = 0; r < 4; ++r) {
                    int p = pbase + s * 16 + lgrp * 4 + r;
                    unsigned w = b1[s][r];
                    float d1 = __uint_as_float(w & 0xFFFFFE00u);
                    float d2 = __uint_as_float(b2[s][r] & 0xFFFFFE00u);
                    float kf = (float)(w & 0x1FFu);
                    out_assign[p] = (d2 - d1 <= MARGIN) ? SENTINEL : kf;
                }
        }
    }
}

// Self-contained rescore (R21 structure, unchanged -- it was correct): stages
// f32 c to LDS, exact np csq from staged rows, centroid passthrough, then
// ballot-scan for sentinels + wave-pair rescore (R20-proven lane-split-k).
__global__ __launch_bounds__(256) void rescore_kernel(const float* __restrict__ x,
                                                      const float* __restrict__ c,
                                                      float* __restrict__ out_c,
                                                      float* __restrict__ out_assign) {
    extern __shared__ char rsm[];
    float* cs = (float*)rsm;                       // [512][68] f32
    float* scsq = (float*)(rsm + KC * CSTRIDE * 4);// 512 f32, exact np csq

    int tid = threadIdx.x;
#pragma unroll
    for (int it = 0; it < 32; ++it) {
        int idx = tid + it * 256;                  // 8192 float4 chunks
        int row = idx >> 4, q = idx & 15;
        float4 v = ((const float4*)(c + row * DD))[q];
        float* d = &cs[row * CSTRIDE + q * 4];
        d[0] = v.x; d[1] = v.y; d[2] = v.z; d[3] = v.w;
    }
    // Centroid passthrough: block b copies 32 float4s (threads 0..31).
    if (tid < 32) {
        int j = blockIdx.x * 32 + tid;             // 8192 float4s total
        ((float4*)out_c)[j] = ((const float4*)c)[j];
    }
    __syncthreads();
    scsq[tid] = csq_pairwise8(&cs[tid * CSTRIDE]);
    scsq[tid + 256] = csq_pairwise8(&cs[(tid + 256) * CSTRIDE]);
    __syncthreads();

    int wid = tid >> 6, lane = tid & 63;
    int range = blockIdx.x * 1024 + wid * 256;     // this wave's 256 points

    for (int seg = 0; seg < 4; ++seg) {
        int wbase = range + seg * 64;
        float v = out_assign[wbase + lane];
        unsigned long long mask = __ballot(v < 0.0f);

        while (mask) {
            int bit0 = __ffsll((long long)mask) - 1;
            mask &= mask - 1;
            int bit1 = bit0;
            if (mask) {                            // pair two flagged points
                bit1 = __ffsll((long long)mask) - 1;
                mask &= mask - 1;
            }
            int iA = wbase + bit0;
            int iB = wbase + bit1;
            const float* xA = x + (size_t)iA * DD; // wave-uniform -> s_loads
            const float* xB = x + (size_t)iB * DD;
            float xsqA = csq_pairwise8(xA);
            float xsqB = csq_pairwise8(xB);

            unsigned long long bA = ~0ull, bB = ~0ull;
#pragma unroll 1
            for (int j = 0; j < 8; ++j) {
                int k = j * 64 + lane;
                const float* crow = &cs[k * CSTRIDE];
                float a0 = 0.f, a1 = 0.f, a2 = 0.f, a3 = 0.f;
                float c0 = 0.f, c1 = 0.f, c2 = 0.f, c3 = 0.f;
#pragma unroll
                for (int q = 0; q < 16; ++q) {
                    float4 cq = *(const float4*)(crow + q * 4);   // LDS b128
                    a0 = __fmaf_rn(xA[4 * q + 0], cq.x, a0);
                    a1 = __fmaf_rn(xA[4 * q + 1], cq.y, a1);
                    a2 = __fmaf_rn(xA[4 * q + 2], cq.z, a2);
                    a3 = __fmaf_rn(xA[4 * q + 3], cq.w, a3);
                    c0 = __fmaf_rn(xB[4 * q + 0], cq.x, c0);
                    c1 = __fmaf_rn(xB[4 * q + 1], cq.y, c1);
                    c2 = __fmaf_rn(xB[4 * q + 2], cq.z, c2);
                    c3 = __fmaf_rn(xB[4 * q + 3], cq.w, c3);
                }
                float sq = scsq[k];
                float accA = __fadd_rn(__fadd_rn(a0, a1), __fadd_rn(a2, a3));
                float accB = __fadd_rn(__fadd_rn(c0, c1), __fadd_rn(c2, c3));
                float dA = __fmaf_rn(-2.0f, accA, __fadd_rn(xsqA, sq));
                float dB = __fmaf_rn(-2.0f, accB, __fadd_rn(xsqB, sq));
                unsigned long long kA =
                    ((unsigned long long)__float_as_uint(dA) << 32) | (unsigned)k;
                unsigned long long kB =
                    ((unsigned long long)__float_as_uint(dB) << 32) | (unsigned)k;
                bA = bA < kA ? bA : kA;
                bB = bB < kB ? bB : kB;
            }
#pragma unroll
            for (int dd = 1; dd < 64; dd <<= 1) {
                unsigned hiA = (unsigned)__shfl_xor((int)(bA >> 32), dd);
                unsigned loA = (unsigned)__shfl_xor((int)(bA & 0xFFFFFFFFull), dd);
                unsigned long long oA = ((unsigned long long)hiA << 32) | loA;
                bA = bA < oA ? bA : oA;
                unsigned hiB = (unsigned)__shfl_xor((int)(bB >> 32), dd);
                unsigned loB = (unsigned)__shfl_xor((int)(bB & 0xFFFFFFFFull), dd);
                unsigned long long oB = ((unsigned long long)hiB << 32) | loB;
                bB = bB < oB ? bB : oB;
            }
            if (lane == 0) {
                out_assign[iA] = (float)(unsigned)(bA & 0xFFFFFFFFull);
                out_assign[iB] = (float)(unsigned)(bB & 0xFFFFFFFFull);
            }
        }
    }
}

extern "C" void kernel_launch(void* const* d_in, const int* in_sizes, int n_in,
                              void* d_out, int out_size, void* d_ws, size_t ws_size,
                              hipStream_t stream) {
    const float* x = (const float*)d_in[0];
    const float* c = (const float*)d_in[1];
    float* out = (float*)d_out;
    float* out_assign = out + KC * DD;

    approx_kernel<<<NPTS / (256 * TILES), ABLOCK, 67584, stream>>>(x, c, out_assign);
    rescore_kernel<<<256, 256, KC * CSTRIDE * 4 + 2048, stream>>>(x, c, out,
                                                                  out_assign);
}